// Round 3
// baseline (812.120 us; speedup 1.0000x reference)
//
#include <hip/hip_runtime.h>
#include <hip/hip_bf16.h>

// L=1024, B=64, K=5, C=128, R=32, E=64, NL=6, NV=2, NF=4, NC=4, POOL=2
// All inputs/outputs are float32.
// 18 k5-conv layers: 0=enc0, 1..5=enc[j], 6=decf0, 7..9=decf[j], 10..17=decv[c][j]

struct Ptrs { const float* p[25]; };

__host__ __device__ inline int w1_off(int l) {
  if (l == 0) return 0;                       // enc0: 1*5*128 = 640
  if (l <= 5) return 640 + (l - 1) * 20480;   // enc:  32*5*128
  if (l == 6) return 103040;                  // decf0: 64*5*128 = 40960
  if (l <= 9) return 144000 + (l - 7) * 20480;
  return 205440 + (l - 10) * 20480;           // decv: 8 layers -> end 369280
}

// float-unit offsets into d_ws; total 6,946,816 floats = 27.8 MB
enum : int {
  OFF_W1T = 0,                        // 369280
  OFF_W2T = 369280,                   // 18*4096 -> 443008
  OFF_CWT = 443008,                   // comp_w^T [192][64] -> 455296
  OFF_B1  = 455296,                   // 18*128 -> 457600
  OFF_B2  = 457600,                   // 18*32  -> 458176
  OFF_CB  = 458176,                   // 64     -> 458240
  OFF_VCW = 458240,                   // 4*192  -> 459008
  OFF_VCB = 459008,                   // 4      -> 459012
  OFF_PACC = 524288,                  // f32 [64][64][512]
  OFF_FACC = 2621440,                 // f32 [64][1024]
  OFF_ACT0 = 2752512,                 // f32 [64][32][1024]
  OFF_ACT1 = 4849664,                 // f32 [64][32][1024]
};

__device__ inline int w1_cin(int l) { return l == 0 ? 1 : (l == 6 ? 64 : 32); }

__device__ inline const float* w1_src(const Ptrs& in, int l) {
  if (l == 0) return in.p[1];
  if (l <= 5) return in.p[5] + (l - 1) * 20480;
  if (l == 6) return in.p[11];
  if (l <= 9) return in.p[15] + (l - 7) * 20480;
  return in.p[19] + (l - 10) * 20480;
}
__device__ inline const float* w2_src(const Ptrs& in, int l) {
  if (l == 0) return in.p[3];
  if (l <= 5) return in.p[7] + (l - 1) * 4096;
  if (l == 6) return in.p[13];
  if (l <= 9) return in.p[17] + (l - 7) * 4096;
  return in.p[21] + (l - 10) * 4096;
}
__device__ inline const float* b1_src(const Ptrs& in, int l) {
  if (l == 0) return in.p[2];
  if (l <= 5) return in.p[6] + (l - 1) * 128;
  if (l == 6) return in.p[12];
  if (l <= 9) return in.p[16] + (l - 7) * 128;
  return in.p[20] + (l - 10) * 128;
}
__device__ inline const float* b2_src(const Ptrs& in, int l) {
  if (l == 0) return in.p[4];
  if (l <= 5) return in.p[8] + (l - 1) * 32;
  if (l == 6) return in.p[14];
  if (l <= 9) return in.p[18] + (l - 7) * 32;
  return in.p[22] + (l - 10) * 32;
}

__device__ inline int sample_id(const float* x, int b) {
  int c = (int)x[b * 1025 + 1024];
  c = c < 0 ? 0 : (c > 3 ? 3 : c);            // defensive: no data-dependent OOB
  return __builtin_amdgcn_readfirstlane(c);
}

// ---- weight prep: transpose to wave-uniform scalar-load layouts ----
__global__ __launch_bounds__(256) void prep_k(Ptrs in, float* __restrict__ ws) {
  const int job = blockIdx.x;
  const int t = threadIdx.x;
  if (job < 18) {
    // w1 [Cout][Cin][K] -> w1t [Cin][K][Cout=128]
    const int cin = w1_cin(job);
    const float* src = w1_src(in, job);
    float* dst = ws + OFF_W1T + w1_off(job);
    const int n = cin * 5 * 128;
    for (int i = t; i < n; i += 256) {
      const int co = i & 127;
      const int tmp = i >> 7;
      const int k = tmp % 5;
      const int ci = tmp / 5;
      dst[i] = src[(co * cin + ci) * 5 + k];
    }
  } else if (job < 36) {
    // w2 [32][128] -> w2t [128][32]
    const int l = job - 18;
    const float* src = w2_src(in, l);
    float* dst = ws + OFF_W2T + l * 4096;
    for (int i = t; i < 4096; i += 256) {
      const int r = i & 31, ci = i >> 5;
      dst[i] = src[r * 128 + ci];
    }
  } else if (job == 36) {
    // comp_w [64][192] -> [192][64]
    const float* src = in.p[9];
    float* dst = ws + OFF_CWT;
    for (int i = t; i < 12288; i += 256) {
      const int e = i & 63, ch = i >> 6;
      dst[i] = src[e * 192 + ch];
    }
  } else {
    for (int i = t; i < 18 * 128; i += 256) {
      const int l = i >> 7, r = i & 127;
      ws[OFF_B1 + i] = b1_src(in, l)[r];
    }
    for (int i = t; i < 18 * 32; i += 256) {
      const int l = i >> 5, r = i & 31;
      ws[OFF_B2 + i] = b2_src(in, l)[r];
    }
    for (int i = t; i < 64; i += 256) ws[OFF_CB + i] = in.p[10][i];
    for (int i = t; i < 768; i += 256) ws[OFF_VCW + i] = in.p[23][i];
    for (int i = t; i < 4; i += 256) ws[OFF_VCB + i] = in.p[24][i];
  }
}

// ---- fused block: conv k=5 dilated (CIN->128) + ReLU + 1x1 (128->32) + ReLU ----
// S=0: src f32 x [B][1025] (CIN=1)
// S=1: src f32 act [B][32][1024]
// S=2: src f32 pacc [B][64][512], nearest-upsample (col>>1)
template <int CIN, int S, bool VAR>
__global__ __launch_bounds__(256) void block_k(
    const float* __restrict__ src,
    const float* __restrict__ w1t, const float* __restrict__ b1f,
    const float* __restrict__ w2t, const float* __restrict__ b2f,
    float* __restrict__ out, int dil,
    const float* __restrict__ x, int jvar) {
  __shared__ float hlds[128 * 64];
  const int lane = threadIdx.x & 63;
  const int wid = __builtin_amdgcn_readfirstlane((int)(threadIdx.x >> 6));
  const int col = blockIdx.x * 64 + lane;
  const int b = blockIdx.y;

  if (VAR) {
    const int lo = sample_id(x, b) * 2 + jvar;
    w1t += lo * 20480; b1f += lo * 128; w2t += lo * 4096; b2f += lo * 32;
  }

  const int co0 = wid * 32;
  float acc[32];
#pragma unroll
  for (int j = 0; j < 32; ++j) acc[j] = b1f[co0 + j];

  for (int ci = 0; ci < CIN; ++ci) {
    float xv[5];
#pragma unroll
    for (int k = 0; k < 5; ++k) {
      const int m = col + (k - 2) * dil;
      const bool ok = (unsigned)m < 1024u;
      float v = 0.f;
      if (ok) {
        if (S == 0)      v = src[b * 1025 + m];
        else if (S == 1) v = src[b * 32768 + ci * 1024 + m];
        else             v = src[b * 32768 + ci * 512 + (m >> 1)];
      }
      xv[k] = v;
    }
    const float* wrow = w1t + ci * 640 + co0;  // [Cin][K][128]
#pragma unroll
    for (int k = 0; k < 5; ++k)
#pragma unroll
      for (int j = 0; j < 32; ++j)
        acc[j] = fmaf(wrow[k * 128 + j], xv[k], acc[j]);
  }

#pragma unroll
  for (int j = 0; j < 32; ++j) hlds[(co0 + j) * 64 + lane] = fmaxf(acc[j], 0.f);
  __syncthreads();

  const int r0 = wid * 8;
  float a2[8];
#pragma unroll
  for (int j = 0; j < 8; ++j) a2[j] = b2f[r0 + j];
  for (int c2 = 0; c2 < 128; ++c2) {
    const float hv = hlds[c2 * 64 + lane];
    const float* w2r = w2t + c2 * 32 + r0;  // [128][32]
#pragma unroll
    for (int j = 0; j < 8; ++j) a2[j] = fmaf(w2r[j], hv, a2[j]);
  }
#pragma unroll
  for (int j = 0; j < 8; ++j)
    out[b * 32768 + (r0 + j) * 1024 + col] = fmaxf(a2[j], 0.f);
}

// ---- comp(1x1, 192->64) + AvgPool(2), accumulated one 32-ch layer at a time ----
template <bool INIT>
__global__ __launch_bounds__(256) void pacc_k(const float* __restrict__ feat,
    const float* __restrict__ cwt_j, const float* __restrict__ cb,
    float* __restrict__ pacc) {
  const int lane = threadIdx.x & 63;
  const int wid = __builtin_amdgcn_readfirstlane((int)(threadIdx.x >> 6));
  const int p = blockIdx.x * 64 + lane;   // pooled col 0..511
  const int b = blockIdx.y;
  const int e0 = wid * 16;
  float* pp = pacc + b * 32768 + p;
  float acc[16];
#pragma unroll
  for (int k = 0; k < 16; ++k) acc[k] = INIT ? cb[e0 + k] : pp[(e0 + k) * 512];
  const float* fb = feat + b * 32768 + 2 * p;
  for (int r = 0; r < 32; ++r) {
    const float2 v = *(const float2*)(fb + r * 1024);
    const float fv = 0.5f * (v.x + v.y);
    const float* w = cwt_j + r * 64 + e0;
#pragma unroll
    for (int k = 0; k < 16; ++k) acc[k] = fmaf(w[k], fv, acc[k]);
  }
#pragma unroll
  for (int k = 0; k < 16; ++k) pp[(e0 + k) * 512] = acc[k];
}

// ---- per-sample final 1x1 (192->1), accumulated one 32-ch layer at a time ----
template <bool INIT, bool LAST>
__global__ __launch_bounds__(256) void facc_k(const float* __restrict__ feat,
    const float* __restrict__ x, const float* __restrict__ vcw,
    const float* __restrict__ vcb, float* __restrict__ facc,
    float* __restrict__ out, int j) {
  const int l = blockIdx.x * 256 + threadIdx.x;
  const int b = blockIdx.y;
  const int c = sample_id(x, b);
  float acc = INIT ? vcb[c] : facc[b * 1024 + l];
  const float* w = vcw + c * 192 + j * 32;
  const float* fb = feat + b * 32768 + l;
  for (int r = 0; r < 32; ++r) acc = fmaf(w[r], fb[r * 1024], acc);
  if (LAST) out[b * 1024 + l] = acc;
  else      facc[b * 1024 + l] = acc;
}

extern "C" void kernel_launch(void* const* d_in, const int* in_sizes, int n_in,
                              void* d_out, int out_size, void* d_ws, size_t ws_size,
                              hipStream_t stream) {
  (void)in_sizes; (void)n_in; (void)out_size; (void)ws_size;
  Ptrs P;
  for (int i = 0; i < 25; ++i) P.p[i] = (const float*)d_in[i];
  const float* x = (const float*)d_in[0];
  float* ws = (float*)d_ws;
  float* pacc = ws + OFF_PACC;
  float* facc = ws + OFF_FACC;
  float* A0 = ws + OFF_ACT0;
  float* A1 = ws + OFF_ACT1;
  auto w1 = [&](int l) { return ws + OFF_W1T + w1_off(l); };
  auto w2 = [&](int l) { return ws + OFF_W2T + l * 4096; };
  auto bb1 = [&](int l) { return ws + OFF_B1 + l * 128; };
  auto bb2 = [&](int l) { return ws + OFF_B2 + l * 32; };
  const float* cwt = ws + OFF_CWT;
  const float* cb = ws + OFF_CB;
  const float* vcw = ws + OFF_VCW;
  const float* vcb = ws + OFF_VCB;
  float* outp = (float*)d_out;

  prep_k<<<dim3(38), dim3(256), 0, stream>>>(P, ws);

  const dim3 bg(16, 64), bt(256);
  const dim3 pg(8, 64), fg(4, 64);

  // ---- encoder ----
  block_k<1, 0, false><<<bg, bt, 0, stream>>>(x, w1(0), bb1(0), w2(0), bb2(0), A0, 1, x, 0);
  pacc_k<true><<<pg, bt, 0, stream>>>(A0, cwt + 0 * 2048, cb, pacc);
  float* cur = A0; float* nxt = A1;
  for (int j = 1; j <= 5; ++j) {
    block_k<32, 1, false><<<bg, bt, 0, stream>>>(cur, w1(j), bb1(j), w2(j), bb2(j),
                                                 nxt, 1 << j, x, 0);
    pacc_k<false><<<pg, bt, 0, stream>>>(nxt, cwt + j * 2048, cb, pacc);
    float* t = cur; cur = nxt; nxt = t;
  }
  // ---- fixed decoder ----
  block_k<64, 2, false><<<bg, bt, 0, stream>>>(pacc, w1(6), bb1(6), w2(6), bb2(6), A0, 32, x, 0);
  facc_k<true, false><<<fg, bt, 0, stream>>>(A0, x, vcw, vcb, facc, outp, 0);
  cur = A0; nxt = A1;
  for (int j = 1; j <= 3; ++j) {
    block_k<32, 1, false><<<bg, bt, 0, stream>>>(cur, w1(6 + j), bb1(6 + j), w2(6 + j),
                                                 bb2(6 + j), nxt, 1 << (5 - j), x, 0);
    facc_k<false, false><<<fg, bt, 0, stream>>>(nxt, x, vcw, vcb, facc, outp, j);
    float* t = cur; cur = nxt; nxt = t;
  }
  // ---- variable decoder (per-sample weights by id) ----
  block_k<32, 1, true><<<bg, bt, 0, stream>>>(cur, w1(10), bb1(10), w2(10), bb2(10),
                                              nxt, 2, x, 0);
  facc_k<false, false><<<fg, bt, 0, stream>>>(nxt, x, vcw, vcb, facc, outp, 4);
  { float* t = cur; cur = nxt; nxt = t; }
  block_k<32, 1, true><<<bg, bt, 0, stream>>>(cur, w1(10), bb1(10), w2(10), bb2(10),
                                              nxt, 1, x, 1);
  facc_k<false, true><<<fg, bt, 0, stream>>>(nxt, x, vcw, vcb, facc, outp, 5);
}

// Round 4
// 550.734 us; speedup vs baseline: 1.4746x; 1.4746x over previous
//
#include <hip/hip_runtime.h>
#include <hip/hip_bf16.h>

typedef unsigned short u16;
typedef short s8v __attribute__((ext_vector_type(8)));   // 8 bf16 (4 VGPRs), per guide §3
typedef float f4v __attribute__((ext_vector_type(4)));

// L=1024, B=64, K=5, C=128, R=32, E=64, NL=6, NV=2, NF=4, NC=4, POOL=2
// All inputs/outputs f32. 18 k5-conv layers: 0=enc0, 1..5=enc, 6=decf0, 7..9=decf, 10..17=decv[c][j]
// Split-bf16: every value v = hi + lo (both bf16); products use 3 MFMAs (hh, hl, lh).

struct Ptrs { const float* p[25]; };

__host__ __device__ inline int qpad_of(int l) { return l == 0 ? 32 : (l == 6 ? 320 : 160); }
__host__ __device__ inline int qoff_of(int l) {
  if (l == 0) return 0;
  if (l <= 5) return 32 + (l - 1) * 160;
  if (l == 6) return 832;
  if (l <= 9) return 1152 + (l - 7) * 160;
  return 1632 + (l - 10) * 160;                // ends 2912
}

// float-unit ws offsets; total 6,946,816 floats = 27.8 MB (same footprint as round 3)
enum : int {
  OFF_W1H = 0,          // u16 [128 x 2912] = 372736 u16 = 186368 fl
  OFF_W1L = 186368,
  OFF_W2H = 372736,     // u16 18*32*128 = 73728 u16 = 36864 fl
  OFF_W2L = 409600,
  OFF_CWT = 446464,     // f32 [192][64]
  OFF_B1  = 458752,     // f32 18*128
  OFF_B2  = 461056,     // f32 18*32
  OFF_CB  = 461632,     // f32 64
  OFF_VCW = 461696,     // f32 4*192
  OFF_VCB = 462464,     // f32 4
  OFF_PACC = 524288,    // f32 [64][64][512]
  OFF_FACC = 2621440,   // f32 [64][1024]
  OFF_ACT0 = 2752512,   // uint [64][32][1024]  (hi|lo<<16 packed bf16 pair)
  OFF_ACT1 = 4849664,   // uint [64][32][1024]
};

__device__ __host__ inline int w1_cin(int l) { return l == 0 ? 1 : (l == 6 ? 64 : 32); }

__device__ inline const float* w1_src(const Ptrs& in, int l) {
  if (l == 0) return in.p[1];
  if (l <= 5) return in.p[5] + (l - 1) * 20480;
  if (l == 6) return in.p[11];
  if (l <= 9) return in.p[15] + (l - 7) * 20480;
  return in.p[19] + (l - 10) * 20480;
}
__device__ inline const float* w2_src(const Ptrs& in, int l) {
  if (l == 0) return in.p[3];
  if (l <= 5) return in.p[7] + (l - 1) * 4096;
  if (l == 6) return in.p[13];
  if (l <= 9) return in.p[17] + (l - 7) * 4096;
  return in.p[21] + (l - 10) * 4096;
}
__device__ inline const float* b1_src(const Ptrs& in, int l) {
  if (l == 0) return in.p[2];
  if (l <= 5) return in.p[6] + (l - 1) * 128;
  if (l == 6) return in.p[12];
  if (l <= 9) return in.p[16] + (l - 7) * 128;
  return in.p[20] + (l - 10) * 128;
}
__device__ inline const float* b2_src(const Ptrs& in, int l) {
  if (l == 0) return in.p[4];
  if (l <= 5) return in.p[8] + (l - 1) * 32;
  if (l == 6) return in.p[14];
  if (l <= 9) return in.p[18] + (l - 7) * 32;
  return in.p[22] + (l - 10) * 32;
}

// RNE f32->bf16 bits and back
__device__ inline u16 f2b(float v) {
  unsigned b = __float_as_uint(v);
  b += 0x7FFFu + ((b >> 16) & 1u);
  return (u16)(b >> 16);
}
__device__ inline float b2fl(u16 h) { return __uint_as_float((unsigned)h << 16); }
__device__ inline void splitf(float v, u16& h, u16& l) {
  h = f2b(v);
  l = f2b(v - b2fl(h));
}

// ---- weight prep: split into hi/lo bf16 planes, transposed layouts ----
__global__ __launch_bounds__(256) void prep_k(Ptrs in, float* __restrict__ ws) {
  const int job = blockIdx.x;
  const int t = threadIdx.x;
  u16* w1h = (u16*)(ws + OFF_W1H);
  u16* w1l = (u16*)(ws + OFF_W1L);
  u16* w2h = (u16*)(ws + OFF_W2H);
  u16* w2l = (u16*)(ws + OFF_W2L);
  if (job < 18) {
    // w1 [Cout][Cin][K] -> [Cout=128][Qpad] with q = ci*5+kk, zero-padded
    const int cin = w1_cin(job);
    const int qp = qpad_of(job);
    const float* src = w1_src(in, job);
    const int base = 128 * qoff_of(job);
    const int n = 128 * qp;
    for (int i = t; i < n; i += 256) {
      const int co = i / qp, q = i % qp;
      const int ci = q / 5, kk = q % 5;
      const float v = (q < cin * 5) ? src[(co * cin + ci) * 5 + kk] : 0.f;
      u16 hh, ll; splitf(v, hh, ll);
      w1h[base + i] = hh; w1l[base + i] = ll;
    }
  } else if (job < 36) {
    // w2 [32][128] kept row-major (already [r][c2])
    const int l = job - 18;
    const float* src = w2_src(in, l);
    for (int i = t; i < 4096; i += 256) {
      u16 hh, ll; splitf(src[i], hh, ll);
      w2h[l * 4096 + i] = hh; w2l[l * 4096 + i] = ll;
    }
  } else if (job == 36) {
    // comp_w [64][192] -> [192][64] f32
    const float* src = in.p[9];
    float* dst = ws + OFF_CWT;
    for (int i = t; i < 12288; i += 256) {
      const int e = i & 63, chn = i >> 6;
      dst[i] = src[e * 192 + chn];
    }
  } else {
    for (int i = t; i < 18 * 128; i += 256) {
      const int l = i >> 7, r = i & 127;
      ws[OFF_B1 + i] = b1_src(in, l)[r];
    }
    for (int i = t; i < 18 * 32; i += 256) {
      const int l = i >> 5, r = i & 31;
      ws[OFF_B2 + i] = b2_src(in, l)[r];
    }
    for (int i = t; i < 64; i += 256) ws[OFF_CB + i] = in.p[10][i];
    for (int i = t; i < 768; i += 256) ws[OFF_VCW + i] = in.p[23][i];
    for (int i = t; i < 4; i += 256) ws[OFF_VCB + i] = in.p[24][i];
  }
}

// ---- MFMA fused block: conv k5 (CIN->128) + ReLU + 1x1 (128->32) + ReLU ----
// S=0: src f32 x [B][1025]; S=1: src uint act [B][32][1024]; S=2: src f32 pacc [B][64][512] upsampled
// out: uint act [B][32][1024] (hi|lo<<16)
template <int CIN, int S, bool VAR>
__global__ __launch_bounds__(256) void blk_k(
    const void* __restrict__ src,
    const u16* __restrict__ w1h, const u16* __restrict__ w1l,
    const u16* __restrict__ w2h, const u16* __restrict__ w2l,
    const float* __restrict__ b1f, const float* __restrict__ b2f,
    unsigned* __restrict__ out, int dil,
    const float* __restrict__ x, int jvar) {
  constexpr int NCH = (CIN == 64) ? 2 : 1;
  constexpr int QC = (CIN == 1) ? 32 : 160;   // q rows per chunk (padded)
  constexpr int QT = QC / 4;                  // q per thread in phase A
  constexpr int KST = QC / 32;                // MFMA k-steps per chunk
  constexpr int QPAD = (CIN == 1) ? 32 : ((CIN == 64) ? 320 : 160);
  __shared__ __align__(16) u16 lds[2 * 64 * 168];  // 43008 B; imc planes, aliased as h planes
  u16* imcH = lds;
  u16* imcL = lds + 64 * 168;

  const int tid = threadIdx.x;
  const int lane = tid & 63;
  const int wid = __builtin_amdgcn_readfirstlane(tid >> 6);
  const int l15 = lane & 15;
  const int g = lane >> 4;
  const int col0 = blockIdx.x * 64;
  const int b = blockIdx.y;

  if (VAR) {
    int c = (int)x[b * 1025 + 1024];
    c = c < 0 ? 0 : (c > 3 ? 3 : c);
    c = __builtin_amdgcn_readfirstlane(c);
    const int lo_ = c * 2 + jvar;           // layer 10+lo_
    w1h += lo_ * 20480; w1l += lo_ * 20480; // 128*160
    w2h += lo_ * 4096;  w2l += lo_ * 4096;
    b1f += lo_ * 128;   b2f += lo_ * 32;
  }

  const int co0 = wid * 32;
  const f4v zf = {0.f, 0.f, 0.f, 0.f};
  f4v acc[2][4];
#pragma unroll
  for (int rt = 0; rt < 2; ++rt)
#pragma unroll
    for (int ct = 0; ct < 4; ++ct) acc[rt][ct] = zf;

  for (int ch = 0; ch < NCH; ++ch) {
    // ---- phase A: im2col hi/lo planes [col][q], stride 168 ----
    {
      const int colw = tid & 63;
      const int qg = tid >> 6;
      const float* sf = (const float*)src;
      const unsigned* su = (const unsigned*)src;
#pragma unroll
      for (int i = 0; i < QT / 4; ++i) {
        unsigned ph0 = 0, ph1 = 0, pl0 = 0, pl1 = 0;
#pragma unroll
        for (int jj = 0; jj < 4; ++jj) {
          const int qq = i * 4 + jj;
          u16 hh = 0, ll = 0;
          int kk, ci; bool valid;
          if (CIN == 1) { kk = qg * QT + qq; ci = 0; valid = (kk < 5); }
          else { ci = qg * (QT / 5) + qq / 5; kk = qq % 5; valid = true; }
          const int m = col0 + colw + (kk - 2) * dil;
          const bool ok = valid && ((unsigned)m < 1024u);
          if (S == 1) {
            const unsigned w = ok ? su[b * 32768 + ci * 1024 + m] : 0u;
            hh = (u16)w; ll = (u16)(w >> 16);
          } else {
            float v = 0.f;
            if (ok) v = (S == 0) ? sf[b * 1025 + m]
                                 : sf[b * 32768 + (ch * 32 + ci) * 512 + (m >> 1)];
            splitf(v, hh, ll);
          }
          if (jj == 0)      { ph0 = hh;                        pl0 = ll; }
          else if (jj == 1) { ph0 |= (unsigned)hh << 16;       pl0 |= (unsigned)ll << 16; }
          else if (jj == 2) { ph1 = hh;                        pl1 = ll; }
          else              { ph1 |= (unsigned)hh << 16;       pl1 |= (unsigned)ll << 16; }
        }
        const int qb = qg * QT + i * 4;
        *(uint2*)&imcH[colw * 168 + qb] = make_uint2(ph0, ph1);
        *(uint2*)&imcL[colw * 168 + qb] = make_uint2(pl0, pl1);
      }
    }
    __syncthreads();

    // ---- conv1 MFMA K-loop ----
    const int qoffw = ch * 160;
#pragma unroll
    for (int ks = 0; ks < KST; ++ks) {
      const int q0 = ks * 32 + 8 * g;
      s8v ah[2], al[2];
#pragma unroll
      for (int rt = 0; rt < 2; ++rt) {
        const int row = co0 + rt * 16 + l15;
        ah[rt] = *(const s8v*)(w1h + row * QPAD + qoffw + q0);
        al[rt] = *(const s8v*)(w1l + row * QPAD + qoffw + q0);
      }
#pragma unroll
      for (int ct = 0; ct < 4; ++ct) {
        const int lb = (ct * 16 + l15) * 168 + q0;
        const s8v bh = *(const s8v*)&imcH[lb];
        const s8v bl = *(const s8v*)&imcL[lb];
#pragma unroll
        for (int rt = 0; rt < 2; ++rt) {
          acc[rt][ct] = __builtin_amdgcn_mfma_f32_16x16x32_bf16(ah[rt], bh, acc[rt][ct], 0, 0, 0);
          acc[rt][ct] = __builtin_amdgcn_mfma_f32_16x16x32_bf16(ah[rt], bl, acc[rt][ct], 0, 0, 0);
          acc[rt][ct] = __builtin_amdgcn_mfma_f32_16x16x32_bf16(al[rt], bh, acc[rt][ct], 0, 0, 0);
        }
      }
    }
    __syncthreads();   // imc free: next chunk build, or h-plane writes below
  }

  // ---- h = relu(conv1 + b1), split to hi/lo planes in LDS [col][c2], stride 168 ----
#pragma unroll
  for (int rt = 0; rt < 2; ++rt) {
#pragma unroll
    for (int ct = 0; ct < 4; ++ct) {
      const int colw = ct * 16 + l15;
      unsigned ph0 = 0, ph1 = 0, pl0 = 0, pl1 = 0;
#pragma unroll
      for (int reg = 0; reg < 4; ++reg) {
        const int c2 = co0 + rt * 16 + 4 * g + reg;
        float hv = acc[rt][ct][reg] + b1f[c2];
        hv = fmaxf(hv, 0.f);
        u16 hh, ll; splitf(hv, hh, ll);
        if (reg == 0)      { ph0 = hh;                  pl0 = ll; }
        else if (reg == 1) { ph0 |= (unsigned)hh << 16; pl0 |= (unsigned)ll << 16; }
        else if (reg == 2) { ph1 = hh;                  pl1 = ll; }
        else               { ph1 |= (unsigned)hh << 16; pl1 |= (unsigned)ll << 16; }
      }
      const int base = colw * 168 + co0 + rt * 16 + 4 * g;
      *(uint2*)&imcH[base] = make_uint2(ph0, ph1);
      *(uint2*)&imcL[base] = make_uint2(pl0, pl1);
    }
  }
  __syncthreads();

  // ---- conv2 MFMA: [32 x 128] x [128 x 64]; wave handles its 16-col slice ----
  f4v acc2[2];
  acc2[0] = zf; acc2[1] = zf;
  const int colw2 = wid * 16 + l15;
#pragma unroll
  for (int ks = 0; ks < 4; ++ks) {
    const int k0 = ks * 32 + 8 * g;
    const int lb = colw2 * 168 + k0;
    const s8v bh = *(const s8v*)&imcH[lb];
    const s8v bl = *(const s8v*)&imcL[lb];
#pragma unroll
    for (int rt = 0; rt < 2; ++rt) {
      const int row = rt * 16 + l15;
      const s8v ah2 = *(const s8v*)(w2h + row * 128 + k0);
      const s8v al2 = *(const s8v*)(w2l + row * 128 + k0);
      acc2[rt] = __builtin_amdgcn_mfma_f32_16x16x32_bf16(ah2, bh, acc2[rt], 0, 0, 0);
      acc2[rt] = __builtin_amdgcn_mfma_f32_16x16x32_bf16(ah2, bl, acc2[rt], 0, 0, 0);
      acc2[rt] = __builtin_amdgcn_mfma_f32_16x16x32_bf16(al2, bh, acc2[rt], 0, 0, 0);
    }
  }
  // ---- out = relu(acc2 + b2) -> packed hi|lo uint act ----
#pragma unroll
  for (int rt = 0; rt < 2; ++rt) {
#pragma unroll
    for (int reg = 0; reg < 4; ++reg) {
      const int r = rt * 16 + 4 * g + reg;
      float v = acc2[rt][reg] + b2f[r];
      v = fmaxf(v, 0.f);
      u16 hh, ll; splitf(v, hh, ll);
      out[b * 32768 + r * 1024 + col0 + colw2] = (unsigned)hh | ((unsigned)ll << 16);
    }
  }
}

// ---- comp(1x1, 192->64) + AvgPool(2), accumulated per 32-ch layer ----
template <bool INIT>
__global__ __launch_bounds__(256) void pacc_k(const unsigned* __restrict__ feat,
    const float* __restrict__ cwt_j, const float* __restrict__ cb,
    float* __restrict__ pacc) {
  const int lane = threadIdx.x & 63;
  const int wid = __builtin_amdgcn_readfirstlane((int)(threadIdx.x >> 6));
  const int p = blockIdx.x * 64 + lane;   // pooled col 0..511
  const int b = blockIdx.y;
  const int e0 = wid * 16;
  float* pp = pacc + b * 32768 + p;
  float acc[16];
#pragma unroll
  for (int k = 0; k < 16; ++k) acc[k] = INIT ? cb[e0 + k] : pp[(e0 + k) * 512];
  const unsigned* fb = feat + b * 32768 + 2 * p;
  for (int r = 0; r < 32; ++r) {
    const uint2 w = *(const uint2*)(fb + r * 1024);
    const float v0 = b2fl((u16)w.x) + b2fl((u16)(w.x >> 16));
    const float v1 = b2fl((u16)w.y) + b2fl((u16)(w.y >> 16));
    const float fv = 0.5f * (v0 + v1);
    const float* w_ = cwt_j + r * 64 + e0;
#pragma unroll
    for (int k = 0; k < 16; ++k) acc[k] = fmaf(w_[k], fv, acc[k]);
  }
#pragma unroll
  for (int k = 0; k < 16; ++k) pp[(e0 + k) * 512] = acc[k];
}

// ---- per-sample final 1x1 (192->1), accumulated per 32-ch layer ----
template <bool INIT, bool LAST>
__global__ __launch_bounds__(256) void facc_k(const unsigned* __restrict__ feat,
    const float* __restrict__ x, const float* __restrict__ vcw,
    const float* __restrict__ vcb, float* __restrict__ facc,
    float* __restrict__ out, int j) {
  const int l = blockIdx.x * 256 + threadIdx.x;
  const int b = blockIdx.y;
  int c = (int)x[b * 1025 + 1024];
  c = c < 0 ? 0 : (c > 3 ? 3 : c);
  c = __builtin_amdgcn_readfirstlane(c);
  float acc = INIT ? vcb[c] : facc[b * 1024 + l];
  const float* w = vcw + c * 192 + j * 32;
  const unsigned* fb = feat + b * 32768 + l;
  for (int r = 0; r < 32; ++r) {
    const unsigned u = fb[r * 1024];
    acc = fmaf(w[r], b2fl((u16)u) + b2fl((u16)(u >> 16)), acc);
  }
  if (LAST) out[b * 1024 + l] = acc;
  else      facc[b * 1024 + l] = acc;
}

extern "C" void kernel_launch(void* const* d_in, const int* in_sizes, int n_in,
                              void* d_out, int out_size, void* d_ws, size_t ws_size,
                              hipStream_t stream) {
  (void)in_sizes; (void)n_in; (void)out_size; (void)ws_size;
  Ptrs P;
  for (int i = 0; i < 25; ++i) P.p[i] = (const float*)d_in[i];
  const float* x = (const float*)d_in[0];
  float* ws = (float*)d_ws;
  float* pacc = ws + OFF_PACC;
  float* facc = ws + OFF_FACC;
  unsigned* A0 = (unsigned*)(ws + OFF_ACT0);
  unsigned* A1 = (unsigned*)(ws + OFF_ACT1);
  auto W1H = [&](int l) { return (const u16*)(ws + OFF_W1H) + 128 * qoff_of(l); };
  auto W1L = [&](int l) { return (const u16*)(ws + OFF_W1L) + 128 * qoff_of(l); };
  auto W2H = [&](int l) { return (const u16*)(ws + OFF_W2H) + l * 4096; };
  auto W2L = [&](int l) { return (const u16*)(ws + OFF_W2L) + l * 4096; };
  auto BB1 = [&](int l) { return (const float*)(ws + OFF_B1) + l * 128; };
  auto BB2 = [&](int l) { return (const float*)(ws + OFF_B2) + l * 32; };
  const float* cwt = ws + OFF_CWT;
  const float* cb = ws + OFF_CB;
  const float* vcw = ws + OFF_VCW;
  const float* vcb = ws + OFF_VCB;
  float* outp = (float*)d_out;

  prep_k<<<dim3(38), dim3(256), 0, stream>>>(P, ws);

  const dim3 bg(16, 64), bt(256);
  const dim3 pg(8, 64), fg(4, 64);

  // ---- encoder ----
  blk_k<1, 0, false><<<bg, bt, 0, stream>>>(x, W1H(0), W1L(0), W2H(0), W2L(0),
                                            BB1(0), BB2(0), A0, 1, x, 0);
  pacc_k<true><<<pg, bt, 0, stream>>>(A0, cwt + 0 * 2048, cb, pacc);
  unsigned* cur = A0; unsigned* nxt = A1;
  for (int j = 1; j <= 5; ++j) {
    blk_k<32, 1, false><<<bg, bt, 0, stream>>>(cur, W1H(j), W1L(j), W2H(j), W2L(j),
                                               BB1(j), BB2(j), nxt, 1 << j, x, 0);
    pacc_k<false><<<pg, bt, 0, stream>>>(nxt, cwt + j * 2048, cb, pacc);
    unsigned* t = cur; cur = nxt; nxt = t;
  }
  // ---- fixed decoder ----
  blk_k<64, 2, false><<<bg, bt, 0, stream>>>(pacc, W1H(6), W1L(6), W2H(6), W2L(6),
                                             BB1(6), BB2(6), A0, 32, x, 0);
  facc_k<true, false><<<fg, bt, 0, stream>>>(A0, x, vcw, vcb, facc, outp, 0);
  cur = A0; nxt = A1;
  for (int j = 1; j <= 3; ++j) {
    blk_k<32, 1, false><<<bg, bt, 0, stream>>>(cur, W1H(6 + j), W1L(6 + j), W2H(6 + j),
                                               W2L(6 + j), BB1(6 + j), BB2(6 + j),
                                               nxt, 1 << (5 - j), x, 0);
    facc_k<false, false><<<fg, bt, 0, stream>>>(nxt, x, vcw, vcb, facc, outp, j);
    unsigned* t = cur; cur = nxt; nxt = t;
  }
  // ---- variable decoder (per-sample weights, base = layer 10) ----
  blk_k<32, 1, true><<<bg, bt, 0, stream>>>(cur, W1H(10), W1L(10), W2H(10), W2L(10),
                                            BB1(10), BB2(10), nxt, 2, x, 0);
  facc_k<false, false><<<fg, bt, 0, stream>>>(nxt, x, vcw, vcb, facc, outp, 4);
  { unsigned* t = cur; cur = nxt; nxt = t; }
  blk_k<32, 1, true><<<bg, bt, 0, stream>>>(cur, W1H(10), W1L(10), W2H(10), W2L(10),
                                            BB1(10), BB2(10), nxt, 1, x, 1);
  facc_k<false, true><<<fg, bt, 0, stream>>>(nxt, x, vcw, vcb, facc, outp, 5);
}

// Round 5
// 467.753 us; speedup vs baseline: 1.7362x; 1.1774x over previous
//
#include <hip/hip_runtime.h>
#include <hip/hip_bf16.h>

typedef unsigned short u16;
typedef short s8v __attribute__((ext_vector_type(8)));   // 8 bf16 (4 VGPRs)
typedef float f4v __attribute__((ext_vector_type(4)));

// L=1024, B=64, K=5, C=128, R=32, E=64, NL=6, NV=2, NF=4, NC=4, POOL=2
// All inputs/outputs f32. 18 k5-conv layers: 0=enc0, 1..5=enc, 6=decf0, 7..9=decf, 10..17=decv[c][j]
// Split-bf16 everywhere: v = hi + lo (both bf16); products use 3 MFMAs (hh, hl, lh).
// comp-conv+pool (pacc) and final per-sample conv (facc) are fused into blk_k's epilogue.

struct Ptrs { const float* p[25]; };

__host__ __device__ inline int qpad_of(int l) { return l == 0 ? 32 : (l == 6 ? 320 : 160); }
__host__ __device__ inline int qoff_of(int l) {
  if (l == 0) return 0;
  if (l <= 5) return 32 + (l - 1) * 160;
  if (l == 6) return 832;
  if (l <= 9) return 1152 + (l - 7) * 160;
  return 1632 + (l - 10) * 160;                // ends 2912
}

// float-unit ws offsets
enum : int {
  OFF_W1H = 0,          // u16 [128 x 2912]
  OFF_W1L = 186368,
  OFF_W2H = 372736,     // u16 18*32*128
  OFF_W2L = 409600,
  OFF_CWT = 446464,     // u16 cwtbH [64][192] then cwtbL [64][192]  (12288 fl total)
  OFF_B1  = 458752,     // f32 18*128
  OFF_B2  = 461056,     // f32 18*32
  OFF_CB  = 461632,     // f32 64
  OFF_VCW = 461696,     // f32 4*192
  OFF_VCB = 462464,     // f32 4
  OFF_PACC = 524288,    // f32 [64][64][512]
  OFF_FACC = 2621440,   // f32 [64][1024]
  OFF_ACT0 = 2752512,   // uint [64][32][1024]  (hi|lo<<16 packed bf16 pair)
  OFF_ACT1 = 4849664,   // uint [64][32][1024]
};

__device__ __host__ inline int w1_cin(int l) { return l == 0 ? 1 : (l == 6 ? 64 : 32); }

__device__ inline const float* w1_src(const Ptrs& in, int l) {
  if (l == 0) return in.p[1];
  if (l <= 5) return in.p[5] + (l - 1) * 20480;
  if (l == 6) return in.p[11];
  if (l <= 9) return in.p[15] + (l - 7) * 20480;
  return in.p[19] + (l - 10) * 20480;
}
__device__ inline const float* w2_src(const Ptrs& in, int l) {
  if (l == 0) return in.p[3];
  if (l <= 5) return in.p[7] + (l - 1) * 4096;
  if (l == 6) return in.p[13];
  if (l <= 9) return in.p[17] + (l - 7) * 4096;
  return in.p[21] + (l - 10) * 4096;
}
__device__ inline const float* b1_src(const Ptrs& in, int l) {
  if (l == 0) return in.p[2];
  if (l <= 5) return in.p[6] + (l - 1) * 128;
  if (l == 6) return in.p[12];
  if (l <= 9) return in.p[16] + (l - 7) * 128;
  return in.p[20] + (l - 10) * 128;
}
__device__ inline const float* b2_src(const Ptrs& in, int l) {
  if (l == 0) return in.p[4];
  if (l <= 5) return in.p[8] + (l - 1) * 32;
  if (l == 6) return in.p[14];
  if (l <= 9) return in.p[18] + (l - 7) * 32;
  return in.p[22] + (l - 10) * 32;
}

__device__ inline u16 f2b(float v) {
  unsigned b = __float_as_uint(v);
  b += 0x7FFFu + ((b >> 16) & 1u);
  return (u16)(b >> 16);
}
__device__ inline float b2fl(u16 h) { return __uint_as_float((unsigned)h << 16); }
__device__ inline void splitf(float v, u16& h, u16& l) {
  h = f2b(v);
  l = f2b(v - b2fl(h));
}

// ---- weight prep: grid (38, 8) for occupancy; slice = blockIdx.y ----
__global__ __launch_bounds__(256) void prep_k(Ptrs in, float* __restrict__ ws) {
  const int job = blockIdx.x;
  const int sl = blockIdx.y;
  const int t = threadIdx.x;
  u16* w1h = (u16*)(ws + OFF_W1H);
  u16* w1l = (u16*)(ws + OFF_W1L);
  u16* w2h = (u16*)(ws + OFF_W2H);
  u16* w2l = (u16*)(ws + OFF_W2L);
  u16* cwH = (u16*)(ws + OFF_CWT);
  u16* cwL = cwH + 12288;
  if (job < 18) {
    // w1 [Cout][Cin][K] -> [Cout=128][Qpad], q = ci*5+kk, zero-padded
    const int cin = w1_cin(job);
    const int qp = qpad_of(job);
    const float* src = w1_src(in, job);
    const int base = 128 * qoff_of(job);
    for (int co = sl * 16; co < sl * 16 + 16; ++co) {
      for (int q = t; q < qp; q += 256) {
        const int ci = q / 5, kk = q % 5;
        const float v = (q < cin * 5) ? src[(co * cin + ci) * 5 + kk] : 0.f;
        u16 hh, ll; splitf(v, hh, ll);
        w1h[base + co * qp + q] = hh; w1l[base + co * qp + q] = ll;
      }
    }
  } else if (job < 36) {
    const int l = job - 18;
    const float* src = w2_src(in, l);
    for (int i = t + sl * 256; i < 4096; i += 2048) {
      u16 hh, ll; splitf(src[i], hh, ll);
      w2h[l * 4096 + i] = hh; w2l[l * 4096 + i] = ll;
    }
  } else if (job == 36) {
    // comp_w [64 e][192 ch] -> bf16 hi/lo planes, layout preserved
    const float* src = in.p[9];
    for (int i = t + sl * 256; i < 12288; i += 2048) {
      u16 hh, ll; splitf(src[i], hh, ll);
      cwH[i] = hh; cwL[i] = ll;
    }
  } else if (sl == 0) {
    for (int i = t; i < 18 * 128; i += 256) {
      const int l = i >> 7, r = i & 127;
      ws[OFF_B1 + i] = b1_src(in, l)[r];
    }
    for (int i = t; i < 18 * 32; i += 256) {
      const int l = i >> 5, r = i & 31;
      ws[OFF_B2 + i] = b2_src(in, l)[r];
    }
    for (int i = t; i < 64; i += 256) ws[OFF_CB + i] = in.p[10][i];
    for (int i = t; i < 768; i += 256) ws[OFF_VCW + i] = in.p[23][i];
    for (int i = t; i < 4; i += 256) ws[OFF_VCB + i] = in.p[24][i];
  }
}

// ---- MFMA fused block: conv k5 (CIN->128) + ReLU + 1x1 (128->32) + ReLU + epilogue ----
// S=0: src f32 x [B][1025]; S=1: src uint act [B][32][1024]; S=2: src f32 pacc upsampled
// EPI: 1=pacc-init 2=pacc-accum 3=facc-init 4=facc-accum 5=facc-accum+store-out
template <int CIN, int S, bool VAR, int EPI>
__global__ __launch_bounds__(256) void blk_k(
    const void* __restrict__ src,
    const u16* __restrict__ w1h, const u16* __restrict__ w1l,
    const u16* __restrict__ w2h, const u16* __restrict__ w2l,
    const float* __restrict__ b1f, const float* __restrict__ b2f,
    unsigned* __restrict__ out, int dil,
    const float* __restrict__ x, int jvar, int jf,
    const u16* __restrict__ cwtbH, const u16* __restrict__ cwtbL,
    const float* __restrict__ cb, float* __restrict__ pacc,
    const float* __restrict__ vcw, const float* __restrict__ vcb,
    float* __restrict__ facc, float* __restrict__ fout) {
  constexpr int NCH = (CIN == 64) ? 2 : 1;
  constexpr int QC = (CIN == 1) ? 32 : 160;
  constexpr int QT = QC / 4;
  constexpr int KST = QC / 32;
  constexpr int QPAD = (CIN == 1) ? 32 : ((CIN == 64) ? 320 : 160);
  __shared__ __align__(16) u16 lds[2 * 64 * 168];  // 43008 B
  u16* imcH = lds;
  u16* imcL = lds + 64 * 168;

  const int tid = threadIdx.x;
  const int lane = tid & 63;
  const int wid = __builtin_amdgcn_readfirstlane(tid >> 6);
  const int l15 = lane & 15;
  const int g = lane >> 4;
  const int col0 = blockIdx.x * 64;
  const int b = blockIdx.y;

  if (VAR) {
    int c = (int)x[b * 1025 + 1024];
    c = c < 0 ? 0 : (c > 3 ? 3 : c);
    c = __builtin_amdgcn_readfirstlane(c);
    const int lo_ = c * 2 + jvar;
    w1h += lo_ * 20480; w1l += lo_ * 20480;
    w2h += lo_ * 4096;  w2l += lo_ * 4096;
    b1f += lo_ * 128;   b2f += lo_ * 32;
  }

  const int co0 = wid * 32;
  const f4v zf = {0.f, 0.f, 0.f, 0.f};
  f4v acc[2][4];
#pragma unroll
  for (int rt = 0; rt < 2; ++rt)
#pragma unroll
    for (int ct = 0; ct < 4; ++ct) acc[rt][ct] = zf;

  for (int ch = 0; ch < NCH; ++ch) {
    // ---- phase A: im2col hi/lo planes [col][q], stride 168 ----
    {
      const int colw = tid & 63;
      const int qg = tid >> 6;
      const float* sf = (const float*)src;
      const unsigned* su = (const unsigned*)src;
#pragma unroll
      for (int i = 0; i < QT / 4; ++i) {
        unsigned ph0 = 0, ph1 = 0, pl0 = 0, pl1 = 0;
#pragma unroll
        for (int jj = 0; jj < 4; ++jj) {
          const int qq = i * 4 + jj;
          u16 hh = 0, ll = 0;
          int kk, ci; bool valid;
          if (CIN == 1) { kk = qg * QT + qq; ci = 0; valid = (kk < 5); }
          else { ci = qg * (QT / 5) + qq / 5; kk = qq % 5; valid = true; }
          const int m = col0 + colw + (kk - 2) * dil;
          const bool ok = valid && ((unsigned)m < 1024u);
          if (S == 1) {
            const unsigned w = ok ? su[b * 32768 + ci * 1024 + m] : 0u;
            hh = (u16)w; ll = (u16)(w >> 16);
          } else {
            float v = 0.f;
            if (ok) v = (S == 0) ? sf[b * 1025 + m]
                                 : sf[b * 32768 + (ch * 32 + ci) * 512 + (m >> 1)];
            splitf(v, hh, ll);
          }
          if (jj == 0)      { ph0 = hh;                        pl0 = ll; }
          else if (jj == 1) { ph0 |= (unsigned)hh << 16;       pl0 |= (unsigned)ll << 16; }
          else if (jj == 2) { ph1 = hh;                        pl1 = ll; }
          else              { ph1 |= (unsigned)hh << 16;       pl1 |= (unsigned)ll << 16; }
        }
        const int qb = qg * QT + i * 4;
        *(uint2*)&imcH[colw * 168 + qb] = make_uint2(ph0, ph1);
        *(uint2*)&imcL[colw * 168 + qb] = make_uint2(pl0, pl1);
      }
    }
    __syncthreads();

    // ---- conv1 MFMA K-loop ----
    const int qoffw = ch * 160;
#pragma unroll
    for (int ks = 0; ks < KST; ++ks) {
      const int q0 = ks * 32 + 8 * g;
      s8v ah[2], al[2];
#pragma unroll
      for (int rt = 0; rt < 2; ++rt) {
        const int row = co0 + rt * 16 + l15;
        ah[rt] = *(const s8v*)(w1h + row * QPAD + qoffw + q0);
        al[rt] = *(const s8v*)(w1l + row * QPAD + qoffw + q0);
      }
#pragma unroll
      for (int ct = 0; ct < 4; ++ct) {
        const int lb = (ct * 16 + l15) * 168 + q0;
        const s8v bh = *(const s8v*)&imcH[lb];
        const s8v bl = *(const s8v*)&imcL[lb];
#pragma unroll
        for (int rt = 0; rt < 2; ++rt) {
          acc[rt][ct] = __builtin_amdgcn_mfma_f32_16x16x32_bf16(ah[rt], bh, acc[rt][ct], 0, 0, 0);
          acc[rt][ct] = __builtin_amdgcn_mfma_f32_16x16x32_bf16(ah[rt], bl, acc[rt][ct], 0, 0, 0);
          acc[rt][ct] = __builtin_amdgcn_mfma_f32_16x16x32_bf16(al[rt], bh, acc[rt][ct], 0, 0, 0);
        }
      }
    }
    __syncthreads();
  }

  // ---- h = relu(conv1 + b1) -> hi/lo planes in LDS [col][c2], stride 168 ----
#pragma unroll
  for (int rt = 0; rt < 2; ++rt) {
#pragma unroll
    for (int ct = 0; ct < 4; ++ct) {
      const int colw = ct * 16 + l15;
      unsigned ph0 = 0, ph1 = 0, pl0 = 0, pl1 = 0;
#pragma unroll
      for (int reg = 0; reg < 4; ++reg) {
        const int c2 = co0 + rt * 16 + 4 * g + reg;
        float hv = fmaxf(acc[rt][ct][reg] + b1f[c2], 0.f);
        u16 hh, ll; splitf(hv, hh, ll);
        if (reg == 0)      { ph0 = hh;                  pl0 = ll; }
        else if (reg == 1) { ph0 |= (unsigned)hh << 16; pl0 |= (unsigned)ll << 16; }
        else if (reg == 2) { ph1 = hh;                  pl1 = ll; }
        else               { ph1 |= (unsigned)hh << 16; pl1 |= (unsigned)ll << 16; }
      }
      const int base = colw * 168 + co0 + rt * 16 + 4 * g;
      *(uint2*)&imcH[base] = make_uint2(ph0, ph1);
      *(uint2*)&imcL[base] = make_uint2(pl0, pl1);
    }
  }
  __syncthreads();

  // ---- conv2 MFMA: out[32 r] x cols; wave handles its 16-col slice ----
  f4v acc2[2];
  acc2[0] = zf; acc2[1] = zf;
  const int colw2 = wid * 16 + l15;
#pragma unroll
  for (int ks = 0; ks < 4; ++ks) {
    const int k0 = ks * 32 + 8 * g;
    const int lb = colw2 * 168 + k0;
    const s8v bh = *(const s8v*)&imcH[lb];
    const s8v bl = *(const s8v*)&imcL[lb];
#pragma unroll
    for (int rt = 0; rt < 2; ++rt) {
      const int row = rt * 16 + l15;
      const s8v ah2 = *(const s8v*)(w2h + row * 128 + k0);
      const s8v al2 = *(const s8v*)(w2l + row * 128 + k0);
      acc2[rt] = __builtin_amdgcn_mfma_f32_16x16x32_bf16(ah2, bh, acc2[rt], 0, 0, 0);
      acc2[rt] = __builtin_amdgcn_mfma_f32_16x16x32_bf16(ah2, bl, acc2[rt], 0, 0, 0);
      acc2[rt] = __builtin_amdgcn_mfma_f32_16x16x32_bf16(al2, bh, acc2[rt], 0, 0, 0);
    }
  }

  // ---- epilogue: act store + fused pacc/facc ----
  float vv[8];
#pragma unroll
  for (int rt = 0; rt < 2; ++rt) {
#pragma unroll
    for (int reg = 0; reg < 4; ++reg) {
      const int r = rt * 16 + 4 * g + reg;
      const float v = fmaxf(acc2[rt][reg] + b2f[r], 0.f);
      vv[rt * 4 + reg] = v;
      u16 hh, ll; splitf(v, hh, ll);
      out[b * 32768 + r * 1024 + col0 + colw2] = (unsigned)hh | ((unsigned)ll << 16);
    }
  }
  __syncthreads();   // all conv2 LDS reads done; imc region reusable

  if (EPI <= 2) {
    // pooled spool [32 p][r] hi/lo planes, stride 40
    u16* spH = lds;
    u16* spL = lds + 1280;
    float vx[8];
#pragma unroll
    for (int i = 0; i < 8; ++i) vx[i] = __shfl_xor(vv[i], 1);
    if (!(l15 & 1)) {
      const int pl = colw2 >> 1;
#pragma unroll
      for (int i = 0; i < 8; ++i) {
        const int rt = i >> 2, reg = i & 3;
        const int r = rt * 16 + 4 * g + reg;
        const float pv = 0.5f * (vv[i] + vx[i]);
        u16 hh, ll; splitf(pv, hh, ll);
        spH[pl * 40 + r] = hh; spL[pl * 40 + r] = ll;
      }
    }
    __syncthreads();
    // pacc contribution: [64 e x 32 r] x [32 r x 32 p] via MFMA
    const u16* cwH = cwtbH + jf * 32;
    const u16* cwL = cwtbL + jf * 32;
    const s8v aH = *(const s8v*)(cwH + (wid * 16 + l15) * 192 + 8 * g);
    const s8v aL = *(const s8v*)(cwL + (wid * 16 + l15) * 192 + 8 * g);
#pragma unroll
    for (int pt = 0; pt < 2; ++pt) {
      const s8v bH = *(const s8v*)(spH + (pt * 16 + l15) * 40 + 8 * g);
      const s8v bL = *(const s8v*)(spL + (pt * 16 + l15) * 40 + 8 * g);
      f4v p = zf;
      p = __builtin_amdgcn_mfma_f32_16x16x32_bf16(aH, bH, p, 0, 0, 0);
      p = __builtin_amdgcn_mfma_f32_16x16x32_bf16(aH, bL, p, 0, 0, 0);
      p = __builtin_amdgcn_mfma_f32_16x16x32_bf16(aL, bH, p, 0, 0, 0);
#pragma unroll
      for (int reg = 0; reg < 4; ++reg) {
        const int e = wid * 16 + 4 * g + reg;
        const int pg = (col0 >> 1) + pt * 16 + l15;
        float* dst = pacc + b * 32768 + e * 512 + pg;
        const float old = (EPI == 1) ? cb[e] : *dst;
        *dst = old + p[reg];
      }
    }
  } else {
    // facc: stage f32 tile [32 r][64 col], wave 0 reduces
    float* ft = (float*)(lds + 4096);
#pragma unroll
    for (int i = 0; i < 8; ++i) {
      const int rt = i >> 2, reg = i & 3;
      const int r = rt * 16 + 4 * g + reg;
      ft[r * 64 + colw2] = vv[i];
    }
    __syncthreads();
    if (wid == 0) {
      int c = (int)x[b * 1025 + 1024];
      c = c < 0 ? 0 : (c > 3 ? 3 : c);
      c = __builtin_amdgcn_readfirstlane(c);
      const float* w = vcw + c * 192 + jf * 32;
      float a = 0.f;
#pragma unroll
      for (int r = 0; r < 32; ++r) a = fmaf(w[r], ft[r * 64 + lane], a);
      float* fd = facc + b * 1024 + col0 + lane;
      a += (EPI == 3) ? vcb[c] : *fd;
      if (EPI == 5) fout[b * 1024 + col0 + lane] = a;
      else          *fd = a;
    }
  }
}

extern "C" void kernel_launch(void* const* d_in, const int* in_sizes, int n_in,
                              void* d_out, int out_size, void* d_ws, size_t ws_size,
                              hipStream_t stream) {
  (void)in_sizes; (void)n_in; (void)out_size; (void)ws_size;
  Ptrs P;
  for (int i = 0; i < 25; ++i) P.p[i] = (const float*)d_in[i];
  const float* x = (const float*)d_in[0];
  float* ws = (float*)d_ws;
  float* pacc = ws + OFF_PACC;
  float* facc = ws + OFF_FACC;
  unsigned* A0 = (unsigned*)(ws + OFF_ACT0);
  unsigned* A1 = (unsigned*)(ws + OFF_ACT1);
  auto W1H = [&](int l) { return (const u16*)(ws + OFF_W1H) + 128 * qoff_of(l); };
  auto W1L = [&](int l) { return (const u16*)(ws + OFF_W1L) + 128 * qoff_of(l); };
  auto W2H = [&](int l) { return (const u16*)(ws + OFF_W2H) + l * 4096; };
  auto W2L = [&](int l) { return (const u16*)(ws + OFF_W2L) + l * 4096; };
  auto BB1 = [&](int l) { return (const float*)(ws + OFF_B1) + l * 128; };
  auto BB2 = [&](int l) { return (const float*)(ws + OFF_B2) + l * 32; };
  const u16* cwtbH = (const u16*)(ws + OFF_CWT);
  const u16* cwtbL = cwtbH + 12288;
  const float* cb = ws + OFF_CB;
  const float* vcw = ws + OFF_VCW;
  const float* vcb = ws + OFF_VCB;
  float* outp = (float*)d_out;

  prep_k<<<dim3(38, 8), dim3(256), 0, stream>>>(P, ws);

  const dim3 bg(16, 64), bt(256);

  // ---- encoder (pacc fused) ----
  blk_k<1, 0, false, 1><<<bg, bt, 0, stream>>>(x, W1H(0), W1L(0), W2H(0), W2L(0),
      BB1(0), BB2(0), A0, 1, x, 0, 0, cwtbH, cwtbL, cb, pacc, vcw, vcb, facc, outp);
  unsigned* cur = A0; unsigned* nxt = A1;
  for (int j = 1; j <= 5; ++j) {
    blk_k<32, 1, false, 2><<<bg, bt, 0, stream>>>(cur, W1H(j), W1L(j), W2H(j), W2L(j),
        BB1(j), BB2(j), nxt, 1 << j, x, 0, j, cwtbH, cwtbL, cb, pacc, vcw, vcb, facc, outp);
    unsigned* t = cur; cur = nxt; nxt = t;
  }
  // ---- fixed decoder (facc fused) ----
  blk_k<64, 2, false, 3><<<bg, bt, 0, stream>>>(pacc, W1H(6), W1L(6), W2H(6), W2L(6),
      BB1(6), BB2(6), A0, 32, x, 0, 0, cwtbH, cwtbL, cb, pacc, vcw, vcb, facc, outp);
  cur = A0; nxt = A1;
  for (int j = 1; j <= 3; ++j) {
    blk_k<32, 1, false, 4><<<bg, bt, 0, stream>>>(cur, W1H(6 + j), W1L(6 + j), W2H(6 + j),
        W2L(6 + j), BB1(6 + j), BB2(6 + j), nxt, 1 << (5 - j), x, 0, j,
        cwtbH, cwtbL, cb, pacc, vcw, vcb, facc, outp);
    unsigned* t = cur; cur = nxt; nxt = t;
  }
  // ---- variable decoder (per-sample weights, base = layer 10) ----
  blk_k<32, 1, true, 4><<<bg, bt, 0, stream>>>(cur, W1H(10), W1L(10), W2H(10), W2L(10),
      BB1(10), BB2(10), nxt, 2, x, 0, 4, cwtbH, cwtbL, cb, pacc, vcw, vcb, facc, outp);
  { unsigned* t = cur; cur = nxt; nxt = t; }
  blk_k<32, 1, true, 5><<<bg, bt, 0, stream>>>(cur, W1H(10), W1L(10), W2H(10), W2L(10),
      BB1(10), BB2(10), nxt, 1, x, 1, 5, cwtbH, cwtbL, cb, pacc, vcw, vcb, facc, outp);
}

// Round 6
// 437.224 us; speedup vs baseline: 1.8574x; 1.0698x over previous
//
#include <hip/hip_runtime.h>
#include <hip/hip_bf16.h>

typedef unsigned short u16;
typedef short s8v __attribute__((ext_vector_type(8)));   // 8 bf16 (4 VGPRs)
typedef float f4v __attribute__((ext_vector_type(4)));

// L=1024, B=64, K=5, C=128, R=32, E=64, NL=6, NV=2, NF=4, NC=4, POOL=2
// All inputs/outputs f32. 18 k5-conv layers: 0=enc0, 1..5=enc, 6=decf0, 7..9=decf, 10..17=decv[c][j]
// Split-bf16: v = hi + lo; products use 3 MFMAs (hh, hl, lh).
// Direct-GEMM conv1 (5 shifted GEMMs over channels) — no im2col, no x-tile LDS.
// Activations in global as [b][col][ci] u16, separate hi/lo planes (channel-contiguous).

struct Ptrs { const float* p[25]; };

// u16-unit offset of layer l inside the w1 plane
__host__ __device__ inline int w1_off16(int l) {
  if (l == 0) return 0;                        // enc0: [128][32 qpad] = 4096
  if (l <= 5) return 4096 + (l - 1) * 20480;   // [5][128][32]
  if (l == 6) return 106496;                   // decf0: [5][128][64] = 40960
  if (l <= 9) return 147456 + (l - 7) * 20480;
  return 208896 + (l - 10) * 20480;            // decv -> ends 372736
}

// float-unit ws offsets
enum : int {
  OFF_W1H = 0,          // u16 372736
  OFF_W1L = 186368,
  OFF_W2H = 372736,     // u16 18*32*128
  OFF_W2L = 409600,
  OFF_CWT = 446464,     // u16 cwtbH [64][192] then cwtbL [64][192]
  OFF_B1  = 458752,     // f32 18*128
  OFF_B2  = 461056,     // f32 18*32
  OFF_CB  = 461632,     // f32 64
  OFF_VCW = 461696,     // f32 4*192
  OFF_VCB = 462464,     // f32 4
  OFF_PACC = 524288,    // f32 [64][64][512]
  OFF_FACC = 2621440,   // f32 [64][1024]
  OFF_ACT0 = 2752512,   // u16 H[64][1024][32] then L[64][1024][32]  (8 MB)
  OFF_ACT1 = 4849664,   // same
};
enum : int { ACT_LOFF = 2097152 };  // u16 offset from H plane to L plane

__device__ __host__ inline int w1_cin(int l) { return l == 0 ? 1 : (l == 6 ? 64 : 32); }

__device__ inline const float* w1_src(const Ptrs& in, int l) {
  if (l == 0) return in.p[1];
  if (l <= 5) return in.p[5] + (l - 1) * 20480;
  if (l == 6) return in.p[11];
  if (l <= 9) return in.p[15] + (l - 7) * 20480;
  return in.p[19] + (l - 10) * 20480;
}
__device__ inline const float* w2_src(const Ptrs& in, int l) {
  if (l == 0) return in.p[3];
  if (l <= 5) return in.p[7] + (l - 1) * 4096;
  if (l == 6) return in.p[13];
  if (l <= 9) return in.p[17] + (l - 7) * 4096;
  return in.p[21] + (l - 10) * 4096;
}
__device__ inline const float* b1_src(const Ptrs& in, int l) {
  if (l == 0) return in.p[2];
  if (l <= 5) return in.p[6] + (l - 1) * 128;
  if (l == 6) return in.p[12];
  if (l <= 9) return in.p[16] + (l - 7) * 128;
  return in.p[20] + (l - 10) * 128;
}
__device__ inline const float* b2_src(const Ptrs& in, int l) {
  if (l == 0) return in.p[4];
  if (l <= 5) return in.p[8] + (l - 1) * 32;
  if (l == 6) return in.p[14];
  if (l <= 9) return in.p[18] + (l - 7) * 32;
  return in.p[22] + (l - 10) * 32;
}

__device__ inline u16 f2b(float v) {
  unsigned b = __float_as_uint(v);
  b += 0x7FFFu + ((b >> 16) & 1u);
  return (u16)(b >> 16);
}
__device__ inline float b2fl(u16 h) { return __uint_as_float((unsigned)h << 16); }
__device__ inline void splitf(float v, u16& h, u16& l) {
  h = f2b(v);
  l = f2b(v - b2fl(h));
}

// ---- weight prep ----
__global__ __launch_bounds__(256) void prep_k(Ptrs in, float* __restrict__ ws) {
  const int job = blockIdx.x;
  const int sl = blockIdx.y;
  const int t = threadIdx.x;
  u16* w1h = (u16*)(ws + OFF_W1H);
  u16* w1l = (u16*)(ws + OFF_W1L);
  u16* w2h = (u16*)(ws + OFF_W2H);
  u16* w2l = (u16*)(ws + OFF_W2L);
  u16* cwH = (u16*)(ws + OFF_CWT);
  u16* cwL = cwH + 12288;
  if (job == 0) {
    // enc0: [co 128][q 32pad], q = tap
    if (sl == 0) {
      const float* src = w1_src(in, 0);
      for (int i = t; i < 4096; i += 256) {
        const int co = i >> 5, q = i & 31;
        const float v = (q < 5) ? src[co * 5 + q] : 0.f;
        u16 hh, ll; splitf(v, hh, ll);
        w1h[i] = hh; w1l[i] = ll;
      }
    }
  } else if (job < 18) {
    // w1 [Cout][Cin][5] -> [tap 5][co 128][ci cin]
    const int cin = w1_cin(job);
    const int lc = (cin == 64) ? 6 : 5;
    const float* src = w1_src(in, job);
    u16* dh = w1h + w1_off16(job);
    u16* dl = w1l + w1_off16(job);
    const int n = 5 * 128 * cin;
    for (int i = t + sl * 256; i < n; i += 2048) {
      const int tap = i >> (7 + lc);
      const int co = (i >> lc) & 127;
      const int ci = i & (cin - 1);
      u16 hh, ll; splitf(src[(co * cin + ci) * 5 + tap], hh, ll);
      dh[i] = hh; dl[i] = ll;
    }
  } else if (job < 36) {
    const int l = job - 18;
    const float* src = w2_src(in, l);
    for (int i = t + sl * 256; i < 4096; i += 2048) {
      u16 hh, ll; splitf(src[i], hh, ll);
      w2h[l * 4096 + i] = hh; w2l[l * 4096 + i] = ll;
    }
  } else if (job == 36) {
    const float* src = in.p[9];
    for (int i = t + sl * 256; i < 12288; i += 2048) {
      u16 hh, ll; splitf(src[i], hh, ll);
      cwH[i] = hh; cwL[i] = ll;
    }
  } else if (sl == 0) {
    for (int i = t; i < 18 * 128; i += 256) {
      const int l = i >> 7, r = i & 127;
      ws[OFF_B1 + i] = b1_src(in, l)[r];
    }
    for (int i = t; i < 18 * 32; i += 256) {
      const int l = i >> 5, r = i & 31;
      ws[OFF_B2 + i] = b2_src(in, l)[r];
    }
    for (int i = t; i < 64; i += 256) ws[OFF_CB + i] = in.p[10][i];
    for (int i = t; i < 768; i += 256) ws[OFF_VCW + i] = in.p[23][i];
    for (int i = t; i < 4; i += 256) ws[OFF_VCB + i] = in.p[24][i];
  }
}

// ---- fused block: conv k5 (CIN->128) + ReLU + 1x1 (128->32) + ReLU + epilogue ----
// S=0: src f32 x [B][1025]; S=1: src u16 actH [b][col][32] (+L plane); S=2: src f32 pacc upsampled
// EPI: 1=pacc-init 2=pacc-accum 3=facc-init 4=facc-accum 5=facc-accum+store-out
template <int CIN, int S, bool VAR, int EPI>
__global__ __launch_bounds__(256, 4) void blk_k(
    const void* __restrict__ src,
    const u16* __restrict__ w1h, const u16* __restrict__ w1l,
    const u16* __restrict__ w2h, const u16* __restrict__ w2l,
    const float* __restrict__ b1f, const float* __restrict__ b2f,
    u16* __restrict__ outH, int dil,
    const float* __restrict__ x, int jvar, int jf,
    const u16* __restrict__ cwtbH, const u16* __restrict__ cwtbL,
    const float* __restrict__ cb, float* __restrict__ pacc,
    const float* __restrict__ vcw, const float* __restrict__ vcb,
    float* __restrict__ facc, float* __restrict__ fout) {
  constexpr int HS = 136;                       // h-tile stride (u16): 272B, 16B-aligned
  __shared__ __align__(16) u16 lds[2 * 64 * HS]; // 34816 B -> 4 blocks/CU
  u16* hH = lds;
  u16* hL = lds + 64 * HS;

  const int tid = threadIdx.x;
  const int lane = tid & 63;
  const int wid = __builtin_amdgcn_readfirstlane(tid >> 6);
  const int l15 = lane & 15;
  const int g = lane >> 4;
  const int col0 = blockIdx.x * 64;
  const int b = blockIdx.y;

  if (VAR) {
    int c = (int)x[b * 1025 + 1024];
    c = c < 0 ? 0 : (c > 3 ? 3 : c);
    c = __builtin_amdgcn_readfirstlane(c);
    const int lo_ = c * 2 + jvar;
    w1h += lo_ * 20480; w1l += lo_ * 20480;
    w2h += lo_ * 4096;  w2l += lo_ * 4096;
    b1f += lo_ * 128;   b2f += lo_ * 32;
  }

  const int co0 = wid * 32;
  const f4v zf = {0.f, 0.f, 0.f, 0.f};
  const s8v z8 = {0, 0, 0, 0, 0, 0, 0, 0};
  f4v acc[2][4];
#pragma unroll
  for (int rt = 0; rt < 2; ++rt)
#pragma unroll
    for (int ct = 0; ct < 4; ++ct) acc[rt][ct] = zf;

  // ---- conv1: direct-GEMM over taps ----
  if (S == 0) {
    // CIN=1: single k-step, k=q (5 valid taps), f32 source + split
    s8v ah[2], al[2];
#pragma unroll
    for (int rt = 0; rt < 2; ++rt) {
      const int row = co0 + rt * 16 + l15;
      ah[rt] = *(const s8v*)(w1h + row * 32 + 8 * g);
      al[rt] = *(const s8v*)(w1l + row * 32 + 8 * g);
    }
    const float* xf = (const float*)src;
#pragma unroll
    for (int ct = 0; ct < 4; ++ct) {
      s8v bh = z8, bl = z8;
#pragma unroll
      for (int j = 0; j < 8; ++j) {
        const int q = 8 * g + j;
        const int m = col0 + ct * 16 + l15 + (q - 2);
        float v = (q < 5 && (unsigned)m < 1024u) ? xf[b * 1025 + m] : 0.f;
        u16 hh, ll; splitf(v, hh, ll);
        bh[j] = (short)hh; bl[j] = (short)ll;
      }
#pragma unroll
      for (int rt = 0; rt < 2; ++rt) {
        acc[rt][ct] = __builtin_amdgcn_mfma_f32_16x16x32_bf16(ah[rt], bh, acc[rt][ct], 0, 0, 0);
        acc[rt][ct] = __builtin_amdgcn_mfma_f32_16x16x32_bf16(ah[rt], bl, acc[rt][ct], 0, 0, 0);
        acc[rt][ct] = __builtin_amdgcn_mfma_f32_16x16x32_bf16(al[rt], bh, acc[rt][ct], 0, 0, 0);
      }
    }
  } else if (S == 1) {
    const u16* aInH = (const u16*)src;
    const u16* aInL = aInH + ACT_LOFF;
#pragma unroll
    for (int tap = 0; tap < 5; ++tap) {
      s8v ah[2], al[2];
#pragma unroll
      for (int rt = 0; rt < 2; ++rt) {
        const int row = co0 + rt * 16 + l15;
        ah[rt] = *(const s8v*)(w1h + (tap * 128 + row) * 32 + 8 * g);
        al[rt] = *(const s8v*)(w1l + (tap * 128 + row) * 32 + 8 * g);
      }
#pragma unroll
      for (int ct = 0; ct < 4; ++ct) {
        const int m = col0 + ct * 16 + l15 + (tap - 2) * dil;
        s8v bh = z8, bl = z8;
        if ((unsigned)m < 1024u) {
          const int off = (b * 1024 + m) * 32 + 8 * g;
          bh = *(const s8v*)(aInH + off);
          bl = *(const s8v*)(aInL + off);
        }
#pragma unroll
        for (int rt = 0; rt < 2; ++rt) {
          acc[rt][ct] = __builtin_amdgcn_mfma_f32_16x16x32_bf16(ah[rt], bh, acc[rt][ct], 0, 0, 0);
          acc[rt][ct] = __builtin_amdgcn_mfma_f32_16x16x32_bf16(ah[rt], bl, acc[rt][ct], 0, 0, 0);
          acc[rt][ct] = __builtin_amdgcn_mfma_f32_16x16x32_bf16(al[rt], bh, acc[rt][ct], 0, 0, 0);
        }
      }
    }
  } else {
    // CIN=64 from f32 pacc (nearest-upsample): 2 channel chunks
    const float* pc = (const float*)src;
#pragma unroll
    for (int tap = 0; tap < 5; ++tap) {
#pragma unroll
      for (int ch = 0; ch < 2; ++ch) {
        s8v ah[2], al[2];
#pragma unroll
        for (int rt = 0; rt < 2; ++rt) {
          const int row = co0 + rt * 16 + l15;
          ah[rt] = *(const s8v*)(w1h + (tap * 128 + row) * 64 + ch * 32 + 8 * g);
          al[rt] = *(const s8v*)(w1l + (tap * 128 + row) * 64 + ch * 32 + 8 * g);
        }
#pragma unroll
        for (int ct = 0; ct < 4; ++ct) {
          const int m = col0 + ct * 16 + l15 + (tap - 2) * dil;
          s8v bh = z8, bl = z8;
          if ((unsigned)m < 1024u) {
            const int pcol = m >> 1;
#pragma unroll
            for (int j = 0; j < 8; ++j) {
              const float v = pc[b * 32768 + (ch * 32 + 8 * g + j) * 512 + pcol];
              u16 hh, ll; splitf(v, hh, ll);
              bh[j] = (short)hh; bl[j] = (short)ll;
            }
          }
#pragma unroll
          for (int rt = 0; rt < 2; ++rt) {
            acc[rt][ct] = __builtin_amdgcn_mfma_f32_16x16x32_bf16(ah[rt], bh, acc[rt][ct], 0, 0, 0);
            acc[rt][ct] = __builtin_amdgcn_mfma_f32_16x16x32_bf16(ah[rt], bl, acc[rt][ct], 0, 0, 0);
            acc[rt][ct] = __builtin_amdgcn_mfma_f32_16x16x32_bf16(al[rt], bh, acc[rt][ct], 0, 0, 0);
          }
        }
      }
    }
  }

  // ---- h = relu(conv1 + b1) -> hi/lo planes in LDS [col][c2] ----
#pragma unroll
  for (int rt = 0; rt < 2; ++rt) {
#pragma unroll
    for (int ct = 0; ct < 4; ++ct) {
      const int colw = ct * 16 + l15;
      unsigned ph0 = 0, ph1 = 0, pl0 = 0, pl1 = 0;
#pragma unroll
      for (int reg = 0; reg < 4; ++reg) {
        const int c2 = co0 + rt * 16 + 4 * g + reg;
        const float hv = fmaxf(acc[rt][ct][reg] + b1f[c2], 0.f);
        u16 hh, ll; splitf(hv, hh, ll);
        if (reg == 0)      { ph0 = hh;                  pl0 = ll; }
        else if (reg == 1) { ph0 |= (unsigned)hh << 16; pl0 |= (unsigned)ll << 16; }
        else if (reg == 2) { ph1 = hh;                  pl1 = ll; }
        else               { ph1 |= (unsigned)hh << 16; pl1 |= (unsigned)ll << 16; }
      }
      const int base = colw * HS + co0 + rt * 16 + 4 * g;
      *(uint2*)&hH[base] = make_uint2(ph0, ph1);
      *(uint2*)&hL[base] = make_uint2(pl0, pl1);
    }
  }
  __syncthreads();

  // ---- conv2 MFMA: wave handles its 16-col slice ----
  f4v acc2[2];
  acc2[0] = zf; acc2[1] = zf;
  const int colw2 = wid * 16 + l15;
#pragma unroll
  for (int ks = 0; ks < 4; ++ks) {
    const int k0 = ks * 32 + 8 * g;
    const s8v bh = *(const s8v*)&hH[colw2 * HS + k0];
    const s8v bl = *(const s8v*)&hL[colw2 * HS + k0];
#pragma unroll
    for (int rt = 0; rt < 2; ++rt) {
      const int row = rt * 16 + l15;
      const s8v ah2 = *(const s8v*)(w2h + row * 128 + k0);
      const s8v al2 = *(const s8v*)(w2l + row * 128 + k0);
      acc2[rt] = __builtin_amdgcn_mfma_f32_16x16x32_bf16(ah2, bh, acc2[rt], 0, 0, 0);
      acc2[rt] = __builtin_amdgcn_mfma_f32_16x16x32_bf16(ah2, bl, acc2[rt], 0, 0, 0);
      acc2[rt] = __builtin_amdgcn_mfma_f32_16x16x32_bf16(al2, bh, acc2[rt], 0, 0, 0);
    }
  }

  // ---- epilogue: act store ([b][col][r] hi/lo planes) + fused pacc/facc ----
  u16* outL = outH + ACT_LOFF;
  float vv[8];
#pragma unroll
  for (int rt = 0; rt < 2; ++rt) {
    unsigned ph0 = 0, ph1 = 0, pl0 = 0, pl1 = 0;
#pragma unroll
    for (int reg = 0; reg < 4; ++reg) {
      const int r = rt * 16 + 4 * g + reg;
      const float v = fmaxf(acc2[rt][reg] + b2f[r], 0.f);
      vv[rt * 4 + reg] = v;
      u16 hh, ll; splitf(v, hh, ll);
      if (reg == 0)      { ph0 = hh;                  pl0 = ll; }
      else if (reg == 1) { ph0 |= (unsigned)hh << 16; pl0 |= (unsigned)ll << 16; }
      else if (reg == 2) { ph1 = hh;                  pl1 = ll; }
      else               { ph1 |= (unsigned)hh << 16; pl1 |= (unsigned)ll << 16; }
    }
    const int ob = (b * 1024 + col0 + colw2) * 32 + rt * 16 + 4 * g;
    *(uint2*)&outH[ob] = make_uint2(ph0, ph1);
    *(uint2*)&outL[ob] = make_uint2(pl0, pl1);
  }
  __syncthreads();   // conv2 LDS reads done; lds reusable

  if (EPI <= 2) {
    // pooled spool [32 p][r] hi/lo planes, stride 40
    u16* spH = lds;
    u16* spL = lds + 1280;
    float vx[8];
#pragma unroll
    for (int i = 0; i < 8; ++i) vx[i] = __shfl_xor(vv[i], 1);
    if (!(l15 & 1)) {
      const int pl = colw2 >> 1;
#pragma unroll
      for (int i = 0; i < 8; ++i) {
        const int rt = i >> 2, reg = i & 3;
        const int r = rt * 16 + 4 * g + reg;
        const float pv = 0.5f * (vv[i] + vx[i]);
        u16 hh, ll; splitf(pv, hh, ll);
        spH[pl * 40 + r] = hh; spL[pl * 40 + r] = ll;
      }
    }
    __syncthreads();
    const u16* cwH = cwtbH + jf * 32;
    const u16* cwL = cwtbL + jf * 32;
    const s8v aH = *(const s8v*)(cwH + (wid * 16 + l15) * 192 + 8 * g);
    const s8v aL = *(const s8v*)(cwL + (wid * 16 + l15) * 192 + 8 * g);
#pragma unroll
    for (int pt = 0; pt < 2; ++pt) {
      const s8v bH = *(const s8v*)(spH + (pt * 16 + l15) * 40 + 8 * g);
      const s8v bL = *(const s8v*)(spL + (pt * 16 + l15) * 40 + 8 * g);
      f4v p = zf;
      p = __builtin_amdgcn_mfma_f32_16x16x32_bf16(aH, bH, p, 0, 0, 0);
      p = __builtin_amdgcn_mfma_f32_16x16x32_bf16(aH, bL, p, 0, 0, 0);
      p = __builtin_amdgcn_mfma_f32_16x16x32_bf16(aL, bH, p, 0, 0, 0);
#pragma unroll
      for (int reg = 0; reg < 4; ++reg) {
        const int e = wid * 16 + 4 * g + reg;
        const int pg = (col0 >> 1) + pt * 16 + l15;
        float* dst = pacc + b * 32768 + e * 512 + pg;
        const float old = (EPI == 1) ? cb[e] : *dst;
        *dst = old + p[reg];
      }
    }
  } else {
    // facc: stage f32 tile [32 r][64 col], wave 0 reduces
    float* ft = (float*)lds;
#pragma unroll
    for (int i = 0; i < 8; ++i) {
      const int rt = i >> 2, reg = i & 3;
      const int r = rt * 16 + 4 * g + reg;
      ft[r * 64 + colw2] = vv[i];
    }
    __syncthreads();
    if (wid == 0) {
      int c = (int)x[b * 1025 + 1024];
      c = c < 0 ? 0 : (c > 3 ? 3 : c);
      c = __builtin_amdgcn_readfirstlane(c);
      const float* w = vcw + c * 192 + jf * 32;
      float a = 0.f;
#pragma unroll
      for (int r = 0; r < 32; ++r) a = fmaf(w[r], ft[r * 64 + lane], a);
      float* fd = facc + b * 1024 + col0 + lane;
      a += (EPI == 3) ? vcb[c] : *fd;
      if (EPI == 5) fout[b * 1024 + col0 + lane] = a;
      else          *fd = a;
    }
  }
}

extern "C" void kernel_launch(void* const* d_in, const int* in_sizes, int n_in,
                              void* d_out, int out_size, void* d_ws, size_t ws_size,
                              hipStream_t stream) {
  (void)in_sizes; (void)n_in; (void)out_size; (void)ws_size;
  Ptrs P;
  for (int i = 0; i < 25; ++i) P.p[i] = (const float*)d_in[i];
  const float* x = (const float*)d_in[0];
  float* ws = (float*)d_ws;
  float* pacc = ws + OFF_PACC;
  float* facc = ws + OFF_FACC;
  u16* A0 = (u16*)(ws + OFF_ACT0);
  u16* A1 = (u16*)(ws + OFF_ACT1);
  auto W1H = [&](int l) { return (const u16*)(ws + OFF_W1H) + w1_off16(l); };
  auto W1L = [&](int l) { return (const u16*)(ws + OFF_W1L) + w1_off16(l); };
  auto W2H = [&](int l) { return (const u16*)(ws + OFF_W2H) + l * 4096; };
  auto W2L = [&](int l) { return (const u16*)(ws + OFF_W2L) + l * 4096; };
  auto BB1 = [&](int l) { return (const float*)(ws + OFF_B1) + l * 128; };
  auto BB2 = [&](int l) { return (const float*)(ws + OFF_B2) + l * 32; };
  const u16* cwtbH = (const u16*)(ws + OFF_CWT);
  const u16* cwtbL = cwtbH + 12288;
  const float* cb = ws + OFF_CB;
  const float* vcw = ws + OFF_VCW;
  const float* vcb = ws + OFF_VCB;
  float* outp = (float*)d_out;

  prep_k<<<dim3(38, 8), dim3(256), 0, stream>>>(P, ws);

  const dim3 bg(16, 64), bt(256);

  // ---- encoder (pacc fused) ----
  blk_k<1, 0, false, 1><<<bg, bt, 0, stream>>>(x, W1H(0), W1L(0), W2H(0), W2L(0),
      BB1(0), BB2(0), A0, 1, x, 0, 0, cwtbH, cwtbL, cb, pacc, vcw, vcb, facc, outp);
  u16* cur = A0; u16* nxt = A1;
  for (int j = 1; j <= 5; ++j) {
    blk_k<32, 1, false, 2><<<bg, bt, 0, stream>>>(cur, W1H(j), W1L(j), W2H(j), W2L(j),
        BB1(j), BB2(j), nxt, 1 << j, x, 0, j, cwtbH, cwtbL, cb, pacc, vcw, vcb, facc, outp);
    u16* t = cur; cur = nxt; nxt = t;
  }
  // ---- fixed decoder (facc fused) ----
  blk_k<64, 2, false, 3><<<bg, bt, 0, stream>>>(pacc, W1H(6), W1L(6), W2H(6), W2L(6),
      BB1(6), BB2(6), A0, 32, x, 0, 0, cwtbH, cwtbL, cb, pacc, vcw, vcb, facc, outp);
  cur = A0; nxt = A1;
  for (int j = 1; j <= 3; ++j) {
    blk_k<32, 1, false, 4><<<bg, bt, 0, stream>>>(cur, W1H(6 + j), W1L(6 + j), W2H(6 + j),
        W2L(6 + j), BB1(6 + j), BB2(6 + j), nxt, 1 << (5 - j), x, 0, j,
        cwtbH, cwtbL, cb, pacc, vcw, vcb, facc, outp);
    u16* t = cur; cur = nxt; nxt = t;
  }
  // ---- variable decoder (per-sample weights, base = layer 10) ----
  blk_k<32, 1, true, 4><<<bg, bt, 0, stream>>>(cur, W1H(10), W1L(10), W2H(10), W2L(10),
      BB1(10), BB2(10), nxt, 2, x, 0, 4, cwtbH, cwtbL, cb, pacc, vcw, vcb, facc, outp);
  { u16* t = cur; cur = nxt; nxt = t; }
  blk_k<32, 1, true, 5><<<bg, bt, 0, stream>>>(cur, W1H(10), W1L(10), W2H(10), W2L(10),
      BB1(10), BB2(10), nxt, 1, x, 1, 5, cwtbH, cwtbL, cb, pacc, vcw, vcb, facc, outp);
}

// Round 8
// 400.546 us; speedup vs baseline: 2.0275x; 1.0916x over previous
//
#include <hip/hip_runtime.h>
#include <hip/hip_bf16.h>

typedef unsigned short u16;
typedef short s8v __attribute__((ext_vector_type(8)));   // 8 bf16 (4 VGPRs)
typedef float f4v __attribute__((ext_vector_type(4)));

// L=1024, B=64, K=5, C=128, R=32, E=64, NL=6, NV=2, NF=4, NC=4, POOL=2
// All inputs/outputs f32. 18 k5-conv layers: 0=enc0, 1..5=enc, 6=decf0, 7..9=decf, 10..17=decv[c][j]
// Split-bf16: v = hi + lo; products use 3 MFMAs (hh, hl, lh).
// Act in global: zero-PADDED [b][1152][32] u16 per plane (cols 64..1087 = real 0..1023).
// blk_k S=1 stages its 192-col halo tile into LDS once (slot-XOR swizzled), conv1 reads LDS.

struct Ptrs { const float* p[25]; };

enum : int { ACT_PLANE = 2359296 };  // u16: 64*1152*32

// u16-unit offset of layer l inside the w1 plane
__host__ __device__ inline int w1_off16(int l) {
  if (l == 0) return 0;                        // enc0: [128][32 qpad] = 4096
  if (l <= 5) return 4096 + (l - 1) * 20480;   // [5][128][32]
  if (l == 6) return 106496;                   // decf0: [5][128][64] = 40960
  if (l <= 9) return 147456 + (l - 7) * 20480;
  return 208896 + (l - 10) * 20480;            // decv -> ends 372736
}

// float-unit ws offsets; total 7,471,104 floats = 29.9 MB
enum : int {
  OFF_W1H = 0,          // u16 372736
  OFF_W1L = 186368,
  OFF_W2H = 372736,     // u16 18*32*128
  OFF_W2L = 409600,
  OFF_CWT = 446464,     // u16 cwtbH [64][192] then cwtbL [64][192]
  OFF_B1  = 458752,     // f32 18*128
  OFF_B2  = 461056,     // f32 18*32
  OFF_CB  = 461632,     // f32 64
  OFF_VCW = 461696,     // f32 4*192
  OFF_VCB = 462464,     // f32 4
  OFF_PACC = 524288,    // f32 [64][64][512]
  OFF_FACC = 2621440,   // f32 [64][1024]
  OFF_ACT0 = 2752512,   // u16 H[64][1152][32] then L plane  (9.4 MB)
  OFF_ACT1 = 5111808,   // same
};

__device__ __host__ inline int w1_cin(int l) { return l == 0 ? 1 : (l == 6 ? 64 : 32); }

__device__ inline const float* w1_src(const Ptrs& in, int l) {
  if (l == 0) return in.p[1];
  if (l <= 5) return in.p[5] + (l - 1) * 20480;
  if (l == 6) return in.p[11];
  if (l <= 9) return in.p[15] + (l - 7) * 20480;
  return in.p[19] + (l - 10) * 20480;
}
__device__ inline const float* w2_src(const Ptrs& in, int l) {
  if (l == 0) return in.p[3];
  if (l <= 5) return in.p[7] + (l - 1) * 4096;
  if (l == 6) return in.p[13];
  if (l <= 9) return in.p[17] + (l - 7) * 4096;
  return in.p[21] + (l - 10) * 4096;
}
__device__ inline const float* b1_src(const Ptrs& in, int l) {
  if (l == 0) return in.p[2];
  if (l <= 5) return in.p[6] + (l - 1) * 128;
  if (l == 6) return in.p[12];
  if (l <= 9) return in.p[16] + (l - 7) * 128;
  return in.p[20] + (l - 10) * 128;
}
__device__ inline const float* b2_src(const Ptrs& in, int l) {
  if (l == 0) return in.p[4];
  if (l <= 5) return in.p[8] + (l - 1) * 32;
  if (l == 6) return in.p[14];
  if (l <= 9) return in.p[18] + (l - 7) * 32;
  return in.p[22] + (l - 10) * 32;
}

__device__ inline u16 f2b(float v) {
  unsigned b = __float_as_uint(v);
  b += 0x7FFFu + ((b >> 16) & 1u);
  return (u16)(b >> 16);
}
__device__ inline float b2fl(u16 h) { return __uint_as_float((unsigned)h << 16); }
__device__ inline void splitf(float v, u16& h, u16& l) {
  h = f2b(v);
  l = f2b(v - b2fl(h));
}

// ---- weight prep + act pad zeroing: grid (40, 8) ----
__global__ __launch_bounds__(256) void prep_k(Ptrs in, float* __restrict__ ws) {
  const int job = blockIdx.x;
  const int sl = blockIdx.y;
  const int t = threadIdx.x;
  u16* w1h = (u16*)(ws + OFF_W1H);
  u16* w1l = (u16*)(ws + OFF_W1L);
  u16* w2h = (u16*)(ws + OFF_W2H);
  u16* w2l = (u16*)(ws + OFF_W2L);
  u16* cwH = (u16*)(ws + OFF_CWT);
  u16* cwL = cwH + 12288;
  if (job == 0) {
    if (sl == 0) {
      const float* src = w1_src(in, 0);
      for (int i = t; i < 4096; i += 256) {
        const int co = i >> 5, q = i & 31;
        const float v = (q < 5) ? src[co * 5 + q] : 0.f;
        u16 hh, ll; splitf(v, hh, ll);
        w1h[i] = hh; w1l[i] = ll;
      }
    }
  } else if (job < 18) {
    // w1 [Cout][Cin][5] -> [tap 5][co 128][ci cin]
    const int cin = w1_cin(job);
    const int lc = (cin == 64) ? 6 : 5;
    const float* src = w1_src(in, job);
    u16* dh = w1h + w1_off16(job);
    u16* dl = w1l + w1_off16(job);
    const int n = 5 * 128 * cin;
    for (int i = t + sl * 256; i < n; i += 2048) {
      const int tap = i >> (7 + lc);
      const int co = (i >> lc) & 127;
      const int ci = i & (cin - 1);
      u16 hh, ll; splitf(src[(co * cin + ci) * 5 + tap], hh, ll);
      dh[i] = hh; dl[i] = ll;
    }
  } else if (job < 36) {
    const int l = job - 18;
    const float* src = w2_src(in, l);
    for (int i = t + sl * 256; i < 4096; i += 2048) {
      u16 hh, ll; splitf(src[i], hh, ll);
      w2h[l * 4096 + i] = hh; w2l[l * 4096 + i] = ll;
    }
  } else if (job == 36) {
    const float* src = in.p[9];
    for (int i = t + sl * 256; i < 12288; i += 2048) {
      u16 hh, ll; splitf(src[i], hh, ll);
      cwH[i] = hh; cwL[i] = ll;
    }
  } else if (job == 37) {
    if (sl == 0) {
      for (int i = t; i < 18 * 128; i += 256) {
        const int l = i >> 7, r = i & 127;
        ws[OFF_B1 + i] = b1_src(in, l)[r];
      }
      for (int i = t; i < 18 * 32; i += 256) {
        const int l = i >> 5, r = i & 31;
        ws[OFF_B2 + i] = b2_src(in, l)[r];
      }
      for (int i = t; i < 64; i += 256) ws[OFF_CB + i] = in.p[10][i];
      for (int i = t; i < 768; i += 256) ws[OFF_VCW + i] = in.p[23][i];
      for (int i = t; i < 4; i += 256) ws[OFF_VCB + i] = in.p[24][i];
    }
  } else {
    // jobs 38/39: zero the pad columns of A0/A1 (both planes)
    u16* A = (u16*)(ws + (job == 38 ? OFF_ACT0 : OFF_ACT1));
    const uint4 z = make_uint4(0, 0, 0, 0);
    for (int i = t; i < 8192; i += 256) {
      const int cid = sl * 8192 + i;           // 0..65535 chunks of 8 u16
      const int p = cid >> 15;
      const int r = cid & 32767;
      const int b = r >> 9;
      const int r2 = r & 511;
      const int pc = r2 >> 2;
      const int slot = r2 & 3;
      const int col = (pc < 64) ? pc : (1024 + pc);
      *(uint4*)&A[p * ACT_PLANE + (b * 1152 + col) * 32 + slot * 8] = z;
    }
  }
}

// ---- fused block: conv k5 (CIN->128) + ReLU + 1x1 (128->32) + ReLU + epilogue ----
// S=0: src f32 x [B][1025]; S=1: src u16 act padded (+L plane); S=2: src f32 pacc upsampled
// EPI: 1=pacc-init 2=pacc-accum 3=facc-init 4=facc-accum 5=facc-accum+store-out
template <int CIN, int S, bool VAR, int EPI>
__global__ __launch_bounds__(256, 4) void blk_k(
    const void* __restrict__ src,
    const u16* __restrict__ w1h, const u16* __restrict__ w1l,
    const u16* __restrict__ w2h, const u16* __restrict__ w2l,
    const float* __restrict__ b1f, const float* __restrict__ b2f,
    u16* __restrict__ outH, int dil,
    const float* __restrict__ x, int jvar, int jf,
    const u16* __restrict__ cwtbH, const u16* __restrict__ cwtbL,
    const float* __restrict__ cb, float* __restrict__ pacc,
    const float* __restrict__ vcw, const float* __restrict__ vcb,
    float* __restrict__ facc, float* __restrict__ fout) {
  constexpr int HS = 136;                        // h-tile stride (u16)
  __shared__ __align__(16) u16 lds[2 * 64 * HS]; // 34816 B; act tile (24576 B) aliases front
  u16* hH = lds;
  u16* hL = lds + 64 * HS;

  const int tid = threadIdx.x;
  const int lane = tid & 63;
  const int wid = __builtin_amdgcn_readfirstlane(tid >> 6);
  const int l15 = lane & 15;
  const int g = lane >> 4;
  const int col0 = blockIdx.x * 64;
  const int b = blockIdx.y;

  if (VAR) {
    int c = (int)x[b * 1025 + 1024];
    c = c < 0 ? 0 : (c > 3 ? 3 : c);
    c = __builtin_amdgcn_readfirstlane(c);
    const int lo_ = c * 2 + jvar;
    w1h += lo_ * 20480; w1l += lo_ * 20480;
    w2h += lo_ * 4096;  w2l += lo_ * 4096;
    b1f += lo_ * 128;   b2f += lo_ * 32;
  }

  const int co0 = wid * 32;
  const f4v zf = {0.f, 0.f, 0.f, 0.f};
  const s8v z8 = {0, 0, 0, 0, 0, 0, 0, 0};
  f4v acc[2][4];
#pragma unroll
  for (int rt = 0; rt < 2; ++rt)
#pragma unroll
    for (int ct = 0; ct < 4; ++ct) acc[rt][ct] = zf;

  if (S == 1) {
    // ---- stage 192-col act halo tile into LDS (slot-XOR swizzle) ----
    const u16* aH = (const u16*)src;
    const int gbase = (b * 1152 + col0) * 32;    // u16
#pragma unroll
    for (int k = 0; k < 3; ++k) {
      const int c2 = tid + k * 256;              // 0..767
      const int q = c2 >> 2, slot = c2 & 3;
      const uint4 v = *(const uint4*)(aH + gbase + c2 * 8);
      *(uint4*)&lds[q * 32 + ((slot ^ (q & 3)) << 3)] = v;
    }
#pragma unroll
    for (int k = 0; k < 3; ++k) {
      const int c2 = tid + k * 256;
      const int q = c2 >> 2, slot = c2 & 3;
      const uint4 v = *(const uint4*)(aH + ACT_PLANE + gbase + c2 * 8);
      *(uint4*)&lds[6144 + q * 32 + ((slot ^ (q & 3)) << 3)] = v;
    }
    __syncthreads();

    // ---- conv1 from LDS ----
#pragma unroll
    for (int tap = 0; tap < 5; ++tap) {
      s8v ah[2], al[2];
#pragma unroll
      for (int rt = 0; rt < 2; ++rt) {
        const int row = co0 + rt * 16 + l15;
        ah[rt] = *(const s8v*)(w1h + (tap * 128 + row) * 32 + 8 * g);
        al[rt] = *(const s8v*)(w1l + (tap * 128 + row) * 32 + 8 * g);
      }
#pragma unroll
      for (int ct = 0; ct < 4; ++ct) {
        const int q = ct * 16 + l15 + (tap - 2) * dil + 64;   // 0..191
        const int off = q * 32 + ((g ^ (q & 3)) << 3);
        const s8v bh = *(const s8v*)&lds[off];
        const s8v bl = *(const s8v*)&lds[6144 + off];
#pragma unroll
        for (int rt = 0; rt < 2; ++rt) {
          acc[rt][ct] = __builtin_amdgcn_mfma_f32_16x16x32_bf16(ah[rt], bh, acc[rt][ct], 0, 0, 0);
          acc[rt][ct] = __builtin_amdgcn_mfma_f32_16x16x32_bf16(ah[rt], bl, acc[rt][ct], 0, 0, 0);
          acc[rt][ct] = __builtin_amdgcn_mfma_f32_16x16x32_bf16(al[rt], bh, acc[rt][ct], 0, 0, 0);
        }
      }
    }
    __syncthreads();   // act tile dead; lds reused for h below
  } else if (S == 0) {
    // CIN=1: single k-step, k=q (5 valid taps), f32 source + split
    s8v ah[2], al[2];
#pragma unroll
    for (int rt = 0; rt < 2; ++rt) {
      const int row = co0 + rt * 16 + l15;
      ah[rt] = *(const s8v*)(w1h + row * 32 + 8 * g);
      al[rt] = *(const s8v*)(w1l + row * 32 + 8 * g);
    }
    const float* xf = (const float*)src;
#pragma unroll
    for (int ct = 0; ct < 4; ++ct) {
      s8v bh = z8, bl = z8;
#pragma unroll
      for (int j = 0; j < 8; ++j) {
        const int q = 8 * g + j;
        const int m = col0 + ct * 16 + l15 + (q - 2);
        float v = (q < 5 && (unsigned)m < 1024u) ? xf[b * 1025 + m] : 0.f;
        u16 hh, ll; splitf(v, hh, ll);
        bh[j] = (short)hh; bl[j] = (short)ll;
      }
#pragma unroll
      for (int rt = 0; rt < 2; ++rt) {
        acc[rt][ct] = __builtin_amdgcn_mfma_f32_16x16x32_bf16(ah[rt], bh, acc[rt][ct], 0, 0, 0);
        acc[rt][ct] = __builtin_amdgcn_mfma_f32_16x16x32_bf16(ah[rt], bl, acc[rt][ct], 0, 0, 0);
        acc[rt][ct] = __builtin_amdgcn_mfma_f32_16x16x32_bf16(al[rt], bh, acc[rt][ct], 0, 0, 0);
      }
    }
  } else {
    // CIN=64 from f32 pacc (nearest-upsample): 2 channel chunks
    const float* pc = (const float*)src;
#pragma unroll
    for (int tap = 0; tap < 5; ++tap) {
#pragma unroll
      for (int ch = 0; ch < 2; ++ch) {
        s8v ah[2], al[2];
#pragma unroll
        for (int rt = 0; rt < 2; ++rt) {
          const int row = co0 + rt * 16 + l15;
          ah[rt] = *(const s8v*)(w1h + (tap * 128 + row) * 64 + ch * 32 + 8 * g);
          al[rt] = *(const s8v*)(w1l + (tap * 128 + row) * 64 + ch * 32 + 8 * g);
        }
#pragma unroll
        for (int ct = 0; ct < 4; ++ct) {
          const int m = col0 + ct * 16 + l15 + (tap - 2) * dil;
          s8v bh = z8, bl = z8;
          if ((unsigned)m < 1024u) {
            const int pcol = m >> 1;
#pragma unroll
            for (int j = 0; j < 8; ++j) {
              const float v = pc[b * 32768 + (ch * 32 + 8 * g + j) * 512 + pcol];
              u16 hh, ll; splitf(v, hh, ll);
              bh[j] = (short)hh; bl[j] = (short)ll;
            }
          }
#pragma unroll
          for (int rt = 0; rt < 2; ++rt) {
            acc[rt][ct] = __builtin_amdgcn_mfma_f32_16x16x32_bf16(ah[rt], bh, acc[rt][ct], 0, 0, 0);
            acc[rt][ct] = __builtin_amdgcn_mfma_f32_16x16x32_bf16(ah[rt], bl, acc[rt][ct], 0, 0, 0);
            acc[rt][ct] = __builtin_amdgcn_mfma_f32_16x16x32_bf16(al[rt], bh, acc[rt][ct], 0, 0, 0);
          }
        }
      }
    }
  }

  // ---- h = relu(conv1 + b1) -> hi/lo planes in LDS [col][c2] ----
#pragma unroll
  for (int rt = 0; rt < 2; ++rt) {
#pragma unroll
    for (int ct = 0; ct < 4; ++ct) {
      const int colw = ct * 16 + l15;
      unsigned ph0 = 0, ph1 = 0, pl0 = 0, pl1 = 0;
#pragma unroll
      for (int reg = 0; reg < 4; ++reg) {
        const int c2 = co0 + rt * 16 + 4 * g + reg;
        const float hv = fmaxf(acc[rt][ct][reg] + b1f[c2], 0.f);
        u16 hh, ll; splitf(hv, hh, ll);
        if (reg == 0)      { ph0 = hh;                  pl0 = ll; }
        else if (reg == 1) { ph0 |= (unsigned)hh << 16; pl0 |= (unsigned)ll << 16; }
        else if (reg == 2) { ph1 = hh;                  pl1 = ll; }
        else               { ph1 |= (unsigned)hh << 16; pl1 |= (unsigned)ll << 16; }
      }
      const int base = colw * HS + co0 + rt * 16 + 4 * g;
      *(uint2*)&hH[base] = make_uint2(ph0, ph1);
      *(uint2*)&hL[base] = make_uint2(pl0, pl1);
    }
  }
  __syncthreads();

  // ---- conv2 MFMA: wave handles its 16-col slice ----
  f4v acc2[2];
  acc2[0] = zf; acc2[1] = zf;
  const int colw2 = wid * 16 + l15;
#pragma unroll
  for (int ks = 0; ks < 4; ++ks) {
    const int k0 = ks * 32 + 8 * g;
    const s8v bh = *(const s8v*)&hH[colw2 * HS + k0];
    const s8v bl = *(const s8v*)&hL[colw2 * HS + k0];
#pragma unroll
    for (int rt = 0; rt < 2; ++rt) {
      const int row = rt * 16 + l15;
      const s8v ah2 = *(const s8v*)(w2h + row * 128 + k0);
      const s8v al2 = *(const s8v*)(w2l + row * 128 + k0);
      acc2[rt] = __builtin_amdgcn_mfma_f32_16x16x32_bf16(ah2, bh, acc2[rt], 0, 0, 0);
      acc2[rt] = __builtin_amdgcn_mfma_f32_16x16x32_bf16(ah2, bl, acc2[rt], 0, 0, 0);
      acc2[rt] = __builtin_amdgcn_mfma_f32_16x16x32_bf16(al2, bh, acc2[rt], 0, 0, 0);
    }
  }

  // ---- epilogue: act store (padded [b][1152][32] planes) + fused pacc/facc ----
  u16* outL = outH + ACT_PLANE;
  float vv[8];
#pragma unroll
  for (int rt = 0; rt < 2; ++rt) {
    unsigned ph0 = 0, ph1 = 0, pl0 = 0, pl1 = 0;
#pragma unroll
    for (int reg = 0; reg < 4; ++reg) {
      const int r = rt * 16 + 4 * g + reg;
      const float v = fmaxf(acc2[rt][reg] + b2f[r], 0.f);
      vv[rt * 4 + reg] = v;
      u16 hh, ll; splitf(v, hh, ll);
      if (reg == 0)      { ph0 = hh;                  pl0 = ll; }
      else if (reg == 1) { ph0 |= (unsigned)hh << 16; pl0 |= (unsigned)ll << 16; }
      else if (reg == 2) { ph1 = hh;                  pl1 = ll; }
      else               { ph1 |= (unsigned)hh << 16; pl1 |= (unsigned)ll << 16; }
    }
    if (EPI != 5) {
      const int ob = (b * 1152 + 64 + col0 + colw2) * 32 + rt * 16 + 4 * g;
      *(uint2*)&outH[ob] = make_uint2(ph0, ph1);
      *(uint2*)&outL[ob] = make_uint2(pl0, pl1);
    }
  }
  __syncthreads();   // conv2 LDS reads done; lds reusable

  if (EPI <= 2) {
    // pooled spool [32 p][r] hi/lo planes, stride 40
    u16* spH = lds;
    u16* spL = lds + 1280;
    float vx[8];
#pragma unroll
    for (int i = 0; i < 8; ++i) vx[i] = __shfl_xor(vv[i], 1);
    if (!(l15 & 1)) {
      const int pl = colw2 >> 1;
#pragma unroll
      for (int i = 0; i < 8; ++i) {
        const int rt = i >> 2, reg = i & 3;
        const int r = rt * 16 + 4 * g + reg;
        const float pv = 0.5f * (vv[i] + vx[i]);
        u16 hh, ll; splitf(pv, hh, ll);
        spH[pl * 40 + r] = hh; spL[pl * 40 + r] = ll;
      }
    }
    __syncthreads();
    const u16* cwH = cwtbH + jf * 32;
    const u16* cwL = cwtbL + jf * 32;
    const s8v aH = *(const s8v*)(cwH + (wid * 16 + l15) * 192 + 8 * g);
    const s8v aL = *(const s8v*)(cwL + (wid * 16 + l15) * 192 + 8 * g);
#pragma unroll
    for (int pt = 0; pt < 2; ++pt) {
      const s8v bH = *(const s8v*)(spH + (pt * 16 + l15) * 40 + 8 * g);
      const s8v bL = *(const s8v*)(spL + (pt * 16 + l15) * 40 + 8 * g);
      f4v p = zf;
      p = __builtin_amdgcn_mfma_f32_16x16x32_bf16(aH, bH, p, 0, 0, 0);
      p = __builtin_amdgcn_mfma_f32_16x16x32_bf16(aH, bL, p, 0, 0, 0);
      p = __builtin_amdgcn_mfma_f32_16x16x32_bf16(aL, bH, p, 0, 0, 0);
#pragma unroll
      for (int reg = 0; reg < 4; ++reg) {
        const int e = wid * 16 + 4 * g + reg;
        const int pg = (col0 >> 1) + pt * 16 + l15;
        float* dst = pacc + b * 32768 + e * 512 + pg;
        const float old = (EPI == 1) ? cb[e] : *dst;
        *dst = old + p[reg];
      }
    }
  } else {
    // facc: stage f32 tile [32 r][64 col], wave 0 reduces
    float* ft = (float*)lds;
#pragma unroll
    for (int i = 0; i < 8; ++i) {
      const int rt = i >> 2, reg = i & 3;
      const int r = rt * 16 + 4 * g + reg;
      ft[r * 64 + colw2] = vv[i];
    }
    __syncthreads();
    if (wid == 0) {
      int c = (int)x[b * 1025 + 1024];
      c = c < 0 ? 0 : (c > 3 ? 3 : c);
      c = __builtin_amdgcn_readfirstlane(c);
      const float* w = vcw + c * 192 + jf * 32;
      float a = 0.f;
#pragma unroll
      for (int r = 0; r < 32; ++r) a = fmaf(w[r], ft[r * 64 + lane], a);
      float* fd = facc + b * 1024 + col0 + lane;
      a += (EPI == 3) ? vcb[c] : *fd;
      if (EPI == 5) fout[b * 1024 + col0 + lane] = a;
      else          *fd = a;
    }
  }
}

extern "C" void kernel_launch(void* const* d_in, const int* in_sizes, int n_in,
                              void* d_out, int out_size, void* d_ws, size_t ws_size,
                              hipStream_t stream) {
  (void)in_sizes; (void)n_in; (void)out_size; (void)ws_size;
  Ptrs P;
  for (int i = 0; i < 25; ++i) P.p[i] = (const float*)d_in[i];
  const float* x = (const float*)d_in[0];
  float* ws = (float*)d_ws;
  float* pacc = ws + OFF_PACC;
  float* facc = ws + OFF_FACC;
  u16* A0 = (u16*)(ws + OFF_ACT0);
  u16* A1 = (u16*)(ws + OFF_ACT1);
  auto W1H = [&](int l) { return (const u16*)(ws + OFF_W1H) + w1_off16(l); };
  auto W1L = [&](int l) { return (const u16*)(ws + OFF_W1L) + w1_off16(l); };
  auto W2H = [&](int l) { return (const u16*)(ws + OFF_W2H) + l * 4096; };
  auto W2L = [&](int l) { return (const u16*)(ws + OFF_W2L) + l * 4096; };
  auto BB1 = [&](int l) { return (const float*)(ws + OFF_B1) + l * 128; };
  auto BB2 = [&](int l) { return (const float*)(ws + OFF_B2) + l * 32; };
  const u16* cwtbH = (const u16*)(ws + OFF_CWT);
  const u16* cwtbL = cwtbH + 12288;
  const float* cb = ws + OFF_CB;
  const float* vcw = ws + OFF_VCW;
  const float* vcb = ws + OFF_VCB;
  float* outp = (float*)d_out;

  prep_k<<<dim3(40, 8), dim3(256), 0, stream>>>(P, ws);

  const dim3 bg(16, 64), bt(256);

  // ---- encoder (pacc fused) ----
  blk_k<1, 0, false, 1><<<bg, bt, 0, stream>>>(x, W1H(0), W1L(0), W2H(0), W2L(0),
      BB1(0), BB2(0), A0, 1, x, 0, 0, cwtbH, cwtbL, cb, pacc, vcw, vcb, facc, outp);
  u16* cur = A0; u16* nxt = A1;
  for (int j = 1; j <= 5; ++j) {
    blk_k<32, 1, false, 2><<<bg, bt, 0, stream>>>(cur, W1H(j), W1L(j), W2H(j), W2L(j),
        BB1(j), BB2(j), nxt, 1 << j, x, 0, j, cwtbH, cwtbL, cb, pacc, vcw, vcb, facc, outp);
    u16* t = cur; cur = nxt; nxt = t;
  }
  // ---- fixed decoder (facc fused) ----
  blk_k<64, 2, false, 3><<<bg, bt, 0, stream>>>(pacc, W1H(6), W1L(6), W2H(6), W2L(6),
      BB1(6), BB2(6), A0, 32, x, 0, 0, cwtbH, cwtbL, cb, pacc, vcw, vcb, facc, outp);
  cur = A0; nxt = A1;
  for (int j = 1; j <= 3; ++j) {
    blk_k<32, 1, false, 4><<<bg, bt, 0, stream>>>(cur, W1H(6 + j), W1L(6 + j), W2H(6 + j),
        W2L(6 + j), BB1(6 + j), BB2(6 + j), nxt, 1 << (5 - j), x, 0, j,
        cwtbH, cwtbL, cb, pacc, vcw, vcb, facc, outp);
    u16* t = cur; cur = nxt; nxt = t;
  }
  // ---- variable decoder (per-sample weights, base = layer 10) ----
  blk_k<32, 1, true, 4><<<bg, bt, 0, stream>>>(cur, W1H(10), W1L(10), W2H(10), W2L(10),
      BB1(10), BB2(10), nxt, 2, x, 0, 4, cwtbH, cwtbL, cb, pacc, vcw, vcb, facc, outp);
  { u16* t = cur; cur = nxt; nxt = t; }
  blk_k<32, 1, true, 5><<<bg, bt, 0, stream>>>(cur, W1H(10), W1L(10), W2H(10), W2L(10),
      BB1(10), BB2(10), nxt, 1, x, 1, 5, cwtbH, cwtbL, cb, pacc, vcw, vcb, facc, outp);
}